// Round 17
// baseline (338.439 us; speedup 1.0000x reference)
//
#include <hip/hip_runtime.h>
#include <hip/hip_bf16.h>
#include <hip/hip_fp16.h>
#include <math.h>

// ---------------- problem constants ----------------
constexpr int Bz  = 32;
constexpr int Nn  = 196;
constexpr int Cc  = 768;
constexpr int Hh  = 12;
constexpr int Dd  = 64;
constexpr int NN2 = Nn * Nn;      // 38416
constexpr int QSZ = Bz * Nn * Cc;          // 4,816,896
constexpr int ATT = Bz * Hh * NN2;         // 14,751,744
constexpr int SAMP = Bz * NN2;    // 1,229,312 samples per BN channel
constexpr float RS = 0.35355339059327373f; // 64^-0.25
// y2 cache geometry: 36*196 = 7056 fp16 per block; blocks 0..6075 cached (batches 0..30)
constexpr int CHUNK = 7056;
constexpr int NCACHE = 6076;      // 31 batches * 196 tiles
constexpr int RA_CAP = 4181;      // chunks in big region
constexpr int RB_CAP = 1365;      // chunks in d_out[0..QSZ) region
constexpr int NLB = NCACHE/2;     // 3038 light-B blocks

typedef short bf16x8 __attribute__((ext_vector_type(8)));
typedef float f32x4  __attribute__((ext_vector_type(4)));

__device__ inline ushort f2b(float f) {
  __hip_bfloat16 h = __float2bfloat16(f);
  return *reinterpret_cast<ushort*>(&h);
}
__device__ inline float b2f(ushort u) {
  union { float f; unsigned i; } x; x.i = ((unsigned)u) << 16; return x.f;
}
__device__ inline ushort f2h_(float f) {
  __half h = __float2half(f);
  return *reinterpret_cast<ushort*>(&h);
}
__device__ inline float h2f_(ushort u) {
  __half h = *reinterpret_cast<__half*>(&u);
  return __half2float(h);
}
__device__ inline const ushort* y2chunk_r(int blk, const ushort* rA, const ushort* rB,
                                          const ushort* rC) {
  if (blk < RA_CAP) return rA + (size_t)blk*CHUNK;
  if (blk < RA_CAP + RB_CAP) return rB + (size_t)(blk - RA_CAP)*CHUNK;
  return rC + (size_t)(blk - RA_CAP - RB_CAP)*CHUNK;
}
__device__ inline ushort* y2chunk_w(int blk, ushort* rA, ushort* rB, ushort* rC) {
  if (blk < RA_CAP) return rA + (size_t)blk*CHUNK;
  if (blk < RA_CAP + RB_CAP) return rB + (size_t)(blk - RA_CAP)*CHUNK;
  return rC + (size_t)(blk - RA_CAP - RB_CAP)*CHUNK;
}

// ---------------- f32 -> bf16 cast (8 elems/thread) ----------------
__global__ __launch_bounds__(256) void k_cast(const float* __restrict__ in,
                                              ushort* __restrict__ outp) {
  const int j = blockIdx.x*256 + threadIdx.x;       // 8-elem group
  float4 a = ((const float4*)in)[2*j];
  float4 b = ((const float4*)in)[2*j+1];
  ushort o[8] = { f2b(a.x), f2b(a.y), f2b(a.z), f2b(a.w),
                  f2b(b.x), f2b(b.y), f2b(b.z), f2b(b.w) };
  ((uint4*)outp)[j] = *(const uint4*)o;
}

// ---------------- bf16 MFMA GEMM: C = A[M,768] x B[N,768]^T ----------------
// EPI 0: qkv epilogue (RS scale q,k; bf16 scatter to [B,H,N,D]); EPI 1: +bias, f32 row-major
template<int EPI>
__global__ __launch_bounds__(256) void k_mfma_gemm(const ushort* __restrict__ A,
                                                   const ushort* __restrict__ B,
                                                   const float* __restrict__ bias,
                                                   void* __restrict__ o0,
                                                   void* __restrict__ o1,
                                                   void* __restrict__ o2) {
  __shared__ ushort As[128*72];
  __shared__ ushort Bs[128*72];
  const int t = threadIdx.x;
  const int m0 = blockIdx.y*128, n0 = blockIdx.x*128;
  const int w = t>>6, lane = t&63;
  const int wr = w>>1, wc = w&1;
  const int lrow = lane&15, lkb = lane>>4;
  f32x4 acc[4][4] = {};
  const int srow = t>>1, skoff = (t&1)*32;
  const ushort* aP = A + (size_t)(m0+srow)*768 + skoff;
  const ushort* bP = B + (size_t)(n0+srow)*768 + skoff;
  ushort* aw = &As[srow*72 + skoff];
  ushort* bw = &Bs[srow*72 + skoff];
  for (int k0 = 0; k0 < 768; k0 += 64) {
    uint4 a0 = *(const uint4*)(aP+k0),    a1 = *(const uint4*)(aP+k0+8);
    uint4 a2 = *(const uint4*)(aP+k0+16), a3 = *(const uint4*)(aP+k0+24);
    uint4 b0 = *(const uint4*)(bP+k0),    b1 = *(const uint4*)(bP+k0+8);
    uint4 b2 = *(const uint4*)(bP+k0+16), b3 = *(const uint4*)(bP+k0+24);
    __syncthreads();
    *(uint4*)(aw)    = a0; *(uint4*)(aw+8)  = a1;
    *(uint4*)(aw+16) = a2; *(uint4*)(aw+24) = a3;
    *(uint4*)(bw)    = b0; *(uint4*)(bw+8)  = b1;
    *(uint4*)(bw+16) = b2; *(uint4*)(bw+24) = b3;
    __syncthreads();
#pragma unroll
    for (int kk = 0; kk < 2; kk++) {
      bf16x8 af[4], bfr[4];
#pragma unroll
      for (int m = 0; m < 4; m++)
        af[m] = *(const bf16x8*)&As[(wr*64+m*16+lrow)*72 + kk*32 + lkb*8];
#pragma unroll
      for (int n = 0; n < 4; n++)
        bfr[n] = *(const bf16x8*)&Bs[(wc*64+n*16+lrow)*72 + kk*32 + lkb*8];
#pragma unroll
      for (int m = 0; m < 4; m++)
#pragma unroll
        for (int n = 0; n < 4; n++)
          acc[m][n] = __builtin_amdgcn_mfma_f32_16x16x32_bf16(af[m], bfr[n], acc[m][n], 0, 0, 0);
    }
  }
  const int r4 = lane>>4;
#pragma unroll
  for (int m = 0; m < 4; m++) {
#pragma unroll
    for (int r = 0; r < 4; r++) {
      const int grow = m0 + wr*64 + m*16 + r4*4 + r;
      if (EPI == 0) {
        ushort* q = (ushort*)o0; ushort* k = (ushort*)o1; ushort* v = (ushort*)o2;
        const int b = grow/196, nn = grow - b*196;
#pragma unroll
        for (int n = 0; n < 4; n++) {
          const int gcol = n0 + wc*64 + n*16 + lrow;
          const int three = gcol/768, rem = gcol - three*768;
          const int h = rem>>6, dd = rem&63;
          float val = acc[m][n][r] * (three < 2 ? RS : 1.0f);
          ushort* base = (three == 0) ? q : (three == 1) ? k : v;
          base[((size_t)(b*12+h)*196 + nn)*64 + dd] = f2b(val);
        }
      } else {
        float* outp = (float*)o0;
#pragma unroll
        for (int n = 0; n < 4; n++) {
          const int gcol = n0 + wc*64 + n*16 + lrow;
          outp[(size_t)grow*768 + gcol] = acc[m][n][r] + bias[gcol];
        }
      }
    }
  }
}

// ---------------- fused QK^T (MFMA) + register softmax -> attn f32 ----------------
__global__ __launch_bounds__(256) void k_qks(const ushort* __restrict__ qb,
                                             const ushort* __restrict__ kb,
                                             float* __restrict__ attn) {
  __shared__ ushort K_lds[208*68];   // 28288 B
  const int t = threadIdx.x;
  const int bh = blockIdx.x;
  const ushort* kp = kb + (size_t)bh*Nn*Dd;
  const ushort* qp = qb + (size_t)bh*Nn*Dd;
  for (int i = t; i < 1568; i += 256) {
    int row = i >> 3, ko = (i & 7)*8;
    *(uint4*)&K_lds[row*68 + ko] = *(const uint4*)(kp + (size_t)row*64 + ko);
  }
  for (int i = t; i < 408; i += 256)
    ((unsigned*)&K_lds[196*68])[i] = 0u;
  __syncthreads();
  const int w = t >> 6, lane = t & 63;
  const int slot = blockIdx.y*4 + w;       // m-tile 0..15 (13..15 idle)
  if (slot >= 13) return;
  const int lrow = lane & 15, lk = lane >> 4;
  int qrow = slot*16 + lrow; if (qrow > 195) qrow = 195;
  bf16x8 aq0 = *(const bf16x8*)(qp + (size_t)qrow*64 + lk*8);
  bf16x8 aq1 = *(const bf16x8*)(qp + (size_t)qrow*64 + 32 + lk*8);
  f32x4 acc[13];
#pragma unroll
  for (int nt = 0; nt < 13; nt++) {
    f32x4 a = {};
    bf16x8 b0 = *(const bf16x8*)&K_lds[(nt*16 + lrow)*68 + lk*8];
    a = __builtin_amdgcn_mfma_f32_16x16x32_bf16(aq0, b0, a, 0, 0, 0);
    bf16x8 b1 = *(const bf16x8*)&K_lds[(nt*16 + lrow)*68 + 32 + lk*8];
    acc[nt] = __builtin_amdgcn_mfma_f32_16x16x32_bf16(aq1, b1, a, 0, 0, 0);
  }
  const bool tailok = (lrow < 4);          // nt==12 valid cols: 192..195
  float inv[4];
#pragma unroll
  for (int r = 0; r < 4; r++) {
    float mx = -1e30f;
#pragma unroll
    for (int nt = 0; nt < 12; nt++) mx = fmaxf(mx, acc[nt][r]);
    if (tailok) mx = fmaxf(mx, acc[12][r]);
    mx = fmaxf(mx, __shfl_xor(mx, 1, 64));
    mx = fmaxf(mx, __shfl_xor(mx, 2, 64));
    mx = fmaxf(mx, __shfl_xor(mx, 4, 64));
    mx = fmaxf(mx, __shfl_xor(mx, 8, 64));
    float s = 0.0f;
#pragma unroll
    for (int nt = 0; nt < 13; nt++) {
      bool valid = (nt < 12) || tailok;
      float e = valid ? __expf(acc[nt][r] - mx) : 0.0f;
      acc[nt][r] = e;
      s += e;
    }
    s += __shfl_xor(s, 1, 64);
    s += __shfl_xor(s, 2, 64);
    s += __shfl_xor(s, 4, 64);
    s += __shfl_xor(s, 8, 64);
    inv[r] = 1.0f / s;
  }
  const int rowb = slot*16 + lk*4;
#pragma unroll
  for (int r = 0; r < 4; r++) {
    const int row = rowb + r;
    if (row < 196) {
      float* op = attn + ((size_t)bh*196 + row)*196;
#pragma unroll
      for (int nt = 0; nt < 13; nt++) {
        int col = nt*16 + lrow;
        if (col < 196) op[col] = acc[nt][r]*inv[r];
      }
    }
  }
}

// ---------------- Gram matrix M[h,h'] = sum attn_h * attn_h' (78 upper-tri) ----------------
__global__ __launch_bounds__(256) void k_gram(const float* __restrict__ attn,
                                              float* __restrict__ part) {
  __shared__ float red2[4*78];
  const int t = threadIdx.x;
  float m[78] = {};
  const int stride = gridDim.x * 256;
  const int NPAIR = SAMP/2;            // 614656
  for (int s = blockIdx.x*256 + t; s < NPAIR; s += stride) {
    int b = s / (NN2/2), p = (s - b*(NN2/2))*2;
    float2 a[12];
#pragma unroll
    for (int h = 0; h < 12; h++)
      a[h] = *(const float2*)&attn[((size_t)(b*12+h))*NN2 + p];
    int idx = 0;
#pragma unroll
    for (int h = 0; h < 12; h++)
#pragma unroll
      for (int h2 = h; h2 < 12; h2++, idx++) {
        m[idx] = fmaf(a[h].x, a[h2].x, m[idx]);
        m[idx] = fmaf(a[h].y, a[h2].y, m[idx]);
      }
  }
#pragma unroll
  for (int i = 0; i < 78; i++) {
#pragma unroll
    for (int off = 32; off; off >>= 1) m[i] += __shfl_xor(m[i], off, 64);
  }
  const int w = t >> 6;
  if ((t & 63) == 0) {
#pragma unroll
    for (int i = 0; i < 78; i++) red2[w*78 + i] = m[i];
  }
  __syncthreads();
  if (t < 78)
    part[(size_t)blockIdx.x*78 + t] = red2[t] + red2[78+t] + red2[156+t] + red2[234+t];
}

// ---------------- hierarchical deterministic reduce ----------------
__global__ __launch_bounds__(256) void k_reduce(const float* __restrict__ part, int nb,
                                               int stride, double* __restrict__ dsum) {
  __shared__ double sh[256];
  const int c = blockIdx.x;
  const int t = threadIdx.x;
  double s = 0.0;
  for (int i = t; i < nb; i += 256) s += (double)part[(size_t)i*stride + c];
  sh[t] = s;
  __syncthreads();
  for (int o = 128; o; o >>= 1) {
    if (t < o) sh[t] += sh[t + o];
    __syncthreads();
  }
  if (t == 0) dsum[c] = sh[0];
}

// ---------------- bn1 affine from Gram (dsum[78]) ----------------
__global__ void k_bn1gram(const double* __restrict__ dsum,
                          const float* __restrict__ w_exp,
                          const float* __restrict__ g, const float* __restrict__ beta,
                          float* __restrict__ stats) {
  int c = threadIdx.x;
  if (c >= 36) return;
  float wv[12];
  float mean = 0.0f;
#pragma unroll
  for (int h = 0; h < 12; h++) { wv[h] = w_exp[c*12+h]; mean += wv[h]; }
  mean *= (1.0f/196.0f);
  double e2 = 0.0;
  int idx = 0;
#pragma unroll
  for (int h = 0; h < 12; h++)
#pragma unroll
    for (int h2 = h; h2 < 12; h2++, idx++) {
      double coef = (double)wv[h] * (double)wv[h2] * (h == h2 ? 1.0 : 2.0);
      e2 += coef * dsum[idx];
    }
  double var = e2 / (double)SAMP - (double)mean*mean;
  float a = g[c] * rsqrtf((float)var + 1e-5f);
  stats[c] = a;
  stats[36 + c] = beta[c] - mean * a;
}

// ---- pass A: expand (halo, 256 thr) + column-sweep dw, 2 groups of 18 ch
//      (dw uses 252/256 threads; barriers 9->6 per block) ----
__global__ __launch_bounds__(256) void k_dlaA(const float* __restrict__ attn,
                                              const float* __restrict__ w_exp,
                                              const float* __restrict__ w_dw,
                                              const float* __restrict__ stats,
                                              ushort* __restrict__ rA,
                                              ushort* __restrict__ rB,
                                              ushort* __restrict__ rC,
                                              float* __restrict__ part) {
  __shared__ float  y_s[18*263];    // stride 263 (mod32=7)
  __shared__ ushort y2l[18*200];    // y2 fp16 transpose-staging
  __shared__ float  sbuf[2*252];    // per-(cl,col) s1/s2 partials
  const int t = threadIdx.x;
  const int blk = blockIdx.x;
  const int b = blk / 196, tile = blk - b*196;
  const int tyq = tile / 14;
  const int ty0 = tyq * 14, tx0 = (tile - tyq*14) * 14;
  const int hy = ty0 + (t >> 4) - 1, hx = tx0 + (t & 15) - 1;
  const bool inb = (hy >= 0) && (hy < 196) && (hx >= 0) && (hx < 196);
  float a[12];
#pragma unroll
  for (int ch = 0; ch < 12; ch++)
    a[ch] = inb ? attn[((size_t)(b*12+ch))*NN2 + (size_t)hy*196 + hx] : 0.0f;

  const bool dwact = (t < 252);
  const int cl = t % 18, col = t / 18;      // dw role: channel-in-group, output column
  ushort* ydst = (blk < NCACHE) ? y2chunk_w(blk, rA, rB, rC) : nullptr;

  for (int g = 0; g < 2; g++) {
    __syncthreads();
#pragma unroll
    for (int c2 = 0; c2 < 18; c2++) {
      const int c = g*18 + c2;
      float y = 0.0f;
#pragma unroll
      for (int h = 0; h < 12; h++) y = fmaf(w_exp[c*12+h], a[h], y);
      y = y*stats[c] + stats[36+c];
      y = fminf(fmaxf(y, 0.0f), 6.0f);
      y_s[c2*263 + t] = inb ? y : 0.0f;
    }
    __syncthreads();
    if (dwact) {
      const int c = g*18 + cl;
      const float* ys = &y_s[cl*263 + col];
      const float* wd = &w_dw[c*9];
      float s1 = 0.0f, s2 = 0.0f;
      ushort y2h[14];
      float r0c0 = ys[0],  r0c1 = ys[1],  r0c2 = ys[2];
      float r1c0 = ys[16], r1c1 = ys[17], r1c2 = ys[18];
#pragma unroll
      for (int r = 0; r < 14; r++) {
        float r2c0 = ys[(r+2)*16], r2c1 = ys[(r+2)*16+1], r2c2 = ys[(r+2)*16+2];
        float y2 = wd[0]*r0c0;
        y2 = fmaf(wd[1], r0c1, y2); y2 = fmaf(wd[2], r0c2, y2);
        y2 = fmaf(wd[3], r1c0, y2); y2 = fmaf(wd[4], r1c1, y2);
        y2 = fmaf(wd[5], r1c2, y2); y2 = fmaf(wd[6], r2c0, y2);
        y2 = fmaf(wd[7], r2c1, y2); y2 = fmaf(wd[8], r2c2, y2);
        s1 += y2; s2 = fmaf(y2, y2, s2);
        y2h[r] = f2h_(y2);
        r0c0 = r1c0; r0c1 = r1c1; r0c2 = r1c2;
        r1c0 = r2c0; r1c1 = r2c1; r1c2 = r2c2;
      }
      sbuf[cl*14 + col] = s1;
      sbuf[252 + cl*14 + col] = s2;
#pragma unroll
      for (int r = 0; r < 14; r++) y2l[cl*200 + r*14 + col] = y2h[r];
    }
    __syncthreads();
    if (ydst) {
      // vectorized readout: 882 uint2 groups (4 ushorts each), 18 ch x 196 px
      for (int i = t; i < 882; i += 256) {
        int c2 = i / 49, q = i - c2*49;
        uint2 v = *(const uint2*)&y2l[c2*200 + q*4];
        *(uint2*)&ydst[g*3528 + c2*196 + q*4] = v;
      }
    }
    if (t < 36) {
      const int cc = t % 18, wh = t / 18;
      float s = 0.0f;
#pragma unroll
      for (int j = 0; j < 14; j++) s += sbuf[wh*252 + cc*14 + j];
      part[(size_t)blk*72 + wh*36 + g*18 + cc] = s;
    }
  }
}

// ---- pass B light: one pixel-pair per thread, 2 chunks per block (grid 3038) ----
__global__ __launch_bounds__(256) void k_dlaBlight(const ushort* __restrict__ rA,
                                                   const ushort* __restrict__ rB,
                                                   const ushort* __restrict__ rC,
                                                   const float* __restrict__ w_pro,
                                                   const float* __restrict__ stats,
                                                   float* __restrict__ zatt,
                                                   float* __restrict__ part) {
  __shared__ float red[4*24];
  const int t = threadIdx.x;
  const int blk = blockIdx.x;            // [0, NLB)
  const bool act = (t < 196);
  float s1[12] = {}, s2[12] = {};
  if (act) {
    const int chunk = blk*2 + (t / 98);  // [0, NCACHE)
    const int j = t % 98;                // pair index within chunk
    const int b = chunk / 196, tile = chunk - b*196;
    const int tyq = tile / 14;
    const int ty0 = tyq*14, tx0 = (tile - tyq*14)*14;
    const int p = 2*j;
    const int r = p / 14, cx = p - r*14; // 14 even -> pair stays in one row
    const ushort* src = y2chunk_r(chunk, rA, rB, rC) + p;
    float z0[12] = {}, z1[12] = {};
#pragma unroll
    for (int c = 0; c < 36; c++) {
      const unsigned u = *(const unsigned*)(src + c*196);
      float ya = h2f_((ushort)(u & 0xffffu));
      float yb = h2f_((ushort)(u >> 16));
      const float A2 = stats[72+c], B2 = stats[108+c];
      ya = fminf(fmaxf(fmaf(ya, A2, B2), 0.0f), 6.0f);
      yb = fminf(fmaxf(fmaf(yb, A2, B2), 0.0f), 6.0f);
#pragma unroll
      for (int cc = 0; cc < 12; cc++) {
        const float wp = w_pro[cc*36 + c];
        z0[cc] = fmaf(wp, ya, z0[cc]);
        z1[cc] = fmaf(wp, yb, z1[cc]);
      }
    }
    const int oy = ty0 + r, ox = tx0 + cx;
#pragma unroll
    for (int cc = 0; cc < 12; cc++) {
      *(float2*)&zatt[((size_t)(b*12+cc))*NN2 + (size_t)oy*196 + ox] =
          make_float2(z0[cc], z1[cc]);
      s1[cc] = z0[cc] + z1[cc];
      s2[cc] = z0[cc]*z0[cc] + z1[cc]*z1[cc];
    }
  }
#pragma unroll
  for (int cc = 0; cc < 12; cc++) {
#pragma unroll
    for (int off = 32; off; off >>= 1) {
      s1[cc] += __shfl_xor(s1[cc], off, 64);
      s2[cc] += __shfl_xor(s2[cc], off, 64);
    }
  }
  const int w = t >> 6;
  if ((t & 63) == 0) {
#pragma unroll
    for (int cc = 0; cc < 12; cc++) {
      red[w*24 + cc] = s1[cc];
      red[w*24 + 12 + cc] = s2[cc];
    }
  }
  __syncthreads();
  if (t < 24)
    part[(size_t)blk*24 + t] = red[t] + red[24+t] + red[48+t] + red[72+t];
}

// ---- pass B heavy: batch-31 full recompute (196 blocks); part rows NLB.. ----
__global__ __launch_bounds__(256) void k_dlaBheavy(const float* __restrict__ attn,
                                                   const float* __restrict__ w_exp,
                                                   const float* __restrict__ w_dw,
                                                   const float* __restrict__ w_pro,
                                                   const float* __restrict__ stats,
                                                   float* __restrict__ z31,
                                                   float* __restrict__ part) {
  __shared__ float y_s[12*256];
  __shared__ float z2[12*200];
  const int t = threadIdx.x;
  const int tile = blockIdx.x;
  const int b = 31;
  const int tyq = tile / 14;
  const int ty0 = tyq * 14, tx0 = (tile - tyq*14) * 14;
  const bool act = (t < 196);
  const int py = t / 14, px = t - py*14;
  const int oy = ty0 + py, ox = tx0 + px;
  float z[12] = {};
  const int hy = ty0 + (t >> 4) - 1, hx = tx0 + (t & 15) - 1;
  const bool inb = (hy >= 0) && (hy < 196) && (hx >= 0) && (hx < 196);
  float a[12];
#pragma unroll
  for (int ch = 0; ch < 12; ch++)
    a[ch] = inb ? attn[((size_t)(b*12+ch))*NN2 + (size_t)hy*196 + hx] : 0.0f;
  const int base = (py+1)*16 + (px+1);
  for (int g = 0; g < 3; g++) {
    __syncthreads();
#pragma unroll
    for (int cl = 0; cl < 12; cl++) {
      const int c = g*12 + cl;
      float y = 0.0f;
#pragma unroll
      for (int h = 0; h < 12; h++) y = fmaf(w_exp[c*12+h], a[h], y);
      y = y*stats[c] + stats[36+c];
      y = fminf(fmaxf(y, 0.0f), 6.0f);
      y_s[cl*256 + t] = inb ? y : 0.0f;
    }
    __syncthreads();
    if (act) {
#pragma unroll
      for (int cl = 0; cl < 12; cl++) {
        const int c = g*12 + cl;
        const float* ys = &y_s[cl*256];
        float y2 = 0.0f;
#pragma unroll
        for (int di = 0; di < 3; di++)
#pragma unroll
          for (int dj = 0; dj < 3; dj++)
            y2 = fmaf(w_dw[c*9 + di*3 + dj], ys[base + (di-1)*16 + (dj-1)], y2);
        float y2c = y2*stats[72+c] + stats[108+c];
        y2c = fminf(fmaxf(y2c, 0.0f), 6.0f);
#pragma unroll
        for (int cc = 0; cc < 12; cc++) z[cc] = fmaf(w_pro[cc*36+c], y2c, z[cc]);
      }
    }
  }
  if (act) {
#pragma unroll
    for (int cc = 0; cc < 12; cc++)
      z31[(size_t)cc*NN2 + (size_t)oy*196 + ox] = z[cc];
  }
  // z stats
  __syncthreads();
  if (act) {
#pragma unroll
    for (int cc = 0; cc < 12; cc++) z2[cc*200 + t] = z[cc];
  }
  __syncthreads();
  const int rs = t >> 3, seg = t & 7;
  const int pix0 = seg*25;
  const int pcnt = (seg == 7) ? 21 : 25;
  if (rs < 24) {
    const int cl = rs % 12, wh = rs / 12;
    float s = 0.0f;
    for (int i = 0; i < pcnt; i++) {
      float v = z2[cl*200 + pix0 + i];
      s += wh ? v*v : v;
    }
    s += __shfl_xor(s, 1, 64);
    s += __shfl_xor(s, 2, 64);
    s += __shfl_xor(s, 4, 64);
    if (seg == 0)
      part[(size_t)(NLB + tile)*24 + wh*12 + cl] = s;
  }
}

// ---------------- dsum -> BN affine (36 ch, bn2) ----------------
__global__ void k_bnaffine36(const double* __restrict__ dsum,
                             const float* __restrict__ g, const float* __restrict__ beta,
                             float* __restrict__ stats, int off) {
  int c = threadIdx.x;
  if (c >= 36) return;
  double m = dsum[c] / (double)SAMP;
  double v = dsum[36 + c] / (double)SAMP - m*m;
  float a = g[c] * rsqrtf((float)v + 1e-5f);
  stats[off + c] = a;
  stats[off + 36 + c] = beta[c] - (float)m * a;
}

// ---------------- combined bn3 + adapt_bn affine (from dsum[24]) ----------------
__global__ void k_bnfinal(const double* __restrict__ dsum,
                          const float* __restrict__ g3, const float* __restrict__ b3,
                          const float* __restrict__ ag, const float* __restrict__ ab,
                          float* __restrict__ stats) {
  int c = threadIdx.x;
  if (c >= 12) return;
  (void)b3;
  double m = dsum[c] / (double)SAMP;
  double v = dsum[12 + c] / (double)SAMP - m*m;
  float r1 = rsqrtf((float)v + 1e-5f);
  float vt = g3[c]*g3[c]*(float)v*r1*r1;
  float r2 = rsqrtf(vt + 1e-5f);
  float A = g3[c]*ag[c]*r1*r2;
  stats[144 + c] = A;
  stats[156 + c] = ab[c] - (float)m*A;
}

// ---------------- V transpose: v16 [BH][196][64] -> vt [BH][64][224] bf16 (zero-pad) ----------------
__global__ __launch_bounds__(256) void k_vt(const ushort* __restrict__ v16,
                                            ushort* __restrict__ vt) {
  __shared__ ushort Vl[196*68];
  const int t = threadIdx.x, bh = blockIdx.x;
  const ushort* vp = v16 + (size_t)bh*Nn*Dd;
  for (int i = t; i < 1568; i += 256) {
    int row = i >> 3, ko = (i & 7)*8;
    *(uint4*)&Vl[row*68 + ko] = *(const uint4*)(vp + (size_t)row*64 + ko);
  }
  __syncthreads();
  ushort* dst = vt + (size_t)bh*64*224;
  for (int i = t; i < 64*28; i += 256) {
    int d = i / 28, q = i - d*28;
    ushort tmp[8];
#pragma unroll
    for (int j = 0; j < 8; j++) {
      int m = q*8 + j;
      tmp[j] = (m < 196) ? Vl[m*68 + d] : (ushort)0;
    }
    *(uint4*)&dst[d*224 + q*8] = *(const uint4*)tmp;
  }
}

// ---------------- MFMA PV: attn_r = z*Af+Bf (f32, in-place for b<31), O = P@Vt -> out_pre bf16 ----------------
__global__ __launch_bounds__(256) void k_pvm(const float* __restrict__ z31,
                                             const ushort* __restrict__ vt,
                                             const float* __restrict__ stats,
                                             float* __restrict__ attn_r,
                                             ushort* __restrict__ out_pre) {
  constexpr int STR = 232;
  __shared__ ushort U[32*STR];         // 14848 B: P tile only
  const int t = threadIdx.x;
  const int bh = blockIdx.x;
  const int r0 = blockIdx.y * 32;
  const int b = bh / 12, h = bh - b*12;
  const float Af = stats[144 + h], Bf = stats[156 + h];
  for (int i = t; i < 32*STR/8; i += 256)
    ((uint4*)U)[i] = make_uint4(0,0,0,0);
  __syncthreads();
  const int nvalid = (r0 + 32 <= 196) ? 32 : (196 - r0);
  float* arp = attn_r + (size_t)bh*NN2 + (size_t)r0*196;
  const float* zp = (b < 31) ? arp : (z31 + (size_t)h*NN2 + (size_t)r0*196);
  for (int idx = t; idx < nvalid*196; idx += 256) {
    int rr = idx / 196, m = idx - rr*196;
    float val = fmaf(zp[(size_t)rr*196 + m], Af, Bf);
    arp[(size_t)rr*196 + m] = val;
    U[rr*STR + m] = f2b(val);
  }
  __syncthreads();
  const int w = t >> 6, lane = t & 63;
  const int mt = w >> 1, ct = w & 1;
  const int lr = lane & 15, lk = lane >> 4;
  const ushort* vbase = vt + (size_t)bh*64*224;
#pragma unroll
  for (int cn = 0; cn < 2; cn++) {
    const int n0 = ct*32 + cn*16;
    f32x4 acc = {};
#pragma unroll
    for (int ks = 0; ks < 7; ks++) {
      bf16x8 af = *(const bf16x8*)&U[(mt*16 + lr)*STR + ks*32 + lk*8];
      bf16x8 bf = *(const bf16x8*)&vbase[(size_t)(n0 + lr)*224 + ks*32 + lk*8];
      acc = __builtin_amdgcn_mfma_f32_16x16x32_bf16(af, bf, acc, 0, 0, 0);
    }
#pragma unroll
    for (int r = 0; r < 4; r++) {
      int row = mt*16 + lk*4 + r;
      if (row < nvalid)
        out_pre[((size_t)(b*196 + r0 + row))*Cc + h*64 + n0 + lr] = f2b(acc[r]);
    }
  }
}

// ---------------- launch ----------------
extern "C" void kernel_launch(void* const* d_in, const int* in_sizes, int n_in,
                              void* d_out, int out_size, void* d_ws, size_t ws_size,
                              hipStream_t stream) {
  (void)in_sizes; (void)n_in; (void)out_size; (void)ws_size;
  const float* x      = (const float*)d_in[0];
  const float* w_qkv  = (const float*)d_in[1];
  const float* w_exp  = (const float*)d_in[2];
  const float* bn1_g  = (const float*)d_in[3];
  const float* bn1_b  = (const float*)d_in[4];
  const float* w_dw   = (const float*)d_in[5];
  const float* bn2_g  = (const float*)d_in[6];
  const float* bn2_b  = (const float*)d_in[7];
  const float* w_pro  = (const float*)d_in[8];
  const float* bn3_g  = (const float*)d_in[9];
  const float* bn3_b  = (const float*)d_in[10];
  const float* abn_g  = (const float*)d_in[11];
  const float* abn_b  = (const float*)d_in[12];
  const float* w_proj = (const float*)d_in[13];
  const float* b_proj = (const float*)d_in[14];

  float* out      = (float*)d_out;
  float* attn_out = out + (size_t)QSZ;      // d_out attn region: attn -> z(b<31) -> attn_r
  float* ws    = (float*)d_ws;
  ushort* vb16 = (ushort*)ws;               // [QSZ ushorts]
  ushort* opb  = (ushort*)ws + (size_t)QSZ; // [QSZ ushorts]: y2 cache rC -> out_pre
  float*  big  = ws + (size_t)QSZ;          // [ATT]: {q,k bf16} -> y2 cache rA
  ushort* qb16 = (ushort*)big;
  ushort* kb16 = qb16 + (size_t)QSZ;
  float* stats = ws + (size_t)QSZ + ATT;    // [256]
  float* part  = stats + 256;               // [6272*72]
  double* dsum = (double*)(part + (size_t)6272*72); // [96]
  float* z31   = (float*)(dsum + 96);       // [12*NN2] batch-31 z aux

  // staging in dead d_out region:
  ushort* xb   = (ushort*)out;              // x bf16
  ushort* wqb  = xb + (size_t)QSZ;          // w_qkv bf16
  ushort* rB   = (ushort*)out;              // y2 cache region B (after gemm<0> consumed xb/wqb)
  ushort* vtb  = (ushort*)out;              // V^T [384][64][224] (after rB consumed by dlaBlight)
  ushort* wpb  = (ushort*)part;             // w_proj bf16 (part dead after last reduce)

  k_cast <<<QSZ/2048, 256, 0, stream>>>(x, xb);
  k_cast <<<(2304*768)/2048, 256, 0, stream>>>(w_qkv, wqb);
  k_mfma_gemm<0><<<dim3(18, 49), 256, 0, stream>>>(xb, wqb, nullptr, qb16, kb16, vb16);
  k_qks      <<<dim3(384, 4), 256, 0, stream>>>(qb16, kb16, attn_out);
  k_gram     <<<2048, 256, 0, stream>>>(attn_out, part);
  k_reduce   <<<78, 256, 0, stream>>>(part, 2048, 78, dsum);
  k_bn1gram  <<<1, 64, 0, stream>>>(dsum, w_exp, bn1_g, bn1_b, stats);
  k_dlaA     <<<6272, 256, 0, stream>>>(attn_out, w_exp, w_dw, stats,
                                        (ushort*)big, rB, opb, part);
  k_reduce   <<<72, 256, 0, stream>>>(part, 6272, 72, dsum);
  k_bnaffine36<<<1, 64, 0, stream>>>(dsum, bn2_g, bn2_b, stats, 72);
  k_dlaBlight<<<NLB, 256, 0, stream>>>((const ushort*)big, rB, opb, w_pro, stats,
                                       attn_out, part);
  k_dlaBheavy<<<196, 256, 0, stream>>>(attn_out, w_exp, w_dw, w_pro, stats, z31, part);
  k_reduce   <<<24, 256, 0, stream>>>(part, NLB + 196, 24, dsum);
  k_bnfinal  <<<1, 64, 0, stream>>>(dsum, bn3_g, bn3_b, abn_g, abn_b, stats);
  k_vt       <<<384, 256, 0, stream>>>(vb16, vtb);                           // rB dead now
  k_cast     <<<(768*768)/2048, 256, 0, stream>>>(w_proj, wpb);
  k_pvm      <<<dim3(384, 7), 256, 0, stream>>>(z31, vtb, stats, attn_out, opb);
  k_mfma_gemm<1><<<dim3(6, 49), 256, 0, stream>>>(opb, wpb, b_proj, out, nullptr, nullptr);
}

// Round 18
// 330.724 us; speedup vs baseline: 1.0233x; 1.0233x over previous
//
#include <hip/hip_runtime.h>
#include <hip/hip_bf16.h>
#include <hip/hip_fp16.h>
#include <math.h>

// ---------------- problem constants ----------------
constexpr int Bz  = 32;
constexpr int Nn  = 196;
constexpr int Cc  = 768;
constexpr int Hh  = 12;
constexpr int Dd  = 64;
constexpr int NN2 = Nn * Nn;      // 38416
constexpr int QSZ = Bz * Nn * Cc;          // 4,816,896
constexpr int ATT = Bz * Hh * NN2;         // 14,751,744
constexpr int SAMP = Bz * NN2;    // 1,229,312 samples per BN channel
constexpr float RS = 0.35355339059327373f; // 64^-0.25
// y2 cache geometry: 36*196 = 7056 fp16 per block; blocks 0..6075 cached (batches 0..30)
constexpr int CHUNK = 7056;
constexpr int NCACHE = 6076;      // 31 batches * 196 tiles
constexpr int RA_CAP = 4181;      // chunks in big region
constexpr int RB_CAP = 1365;      // chunks in d_out[0..QSZ) region
constexpr int NLB = NCACHE/2;     // 3038 light-B blocks

typedef short bf16x8 __attribute__((ext_vector_type(8)));
typedef float f32x4  __attribute__((ext_vector_type(4)));

__device__ inline ushort f2b(float f) {
  __hip_bfloat16 h = __float2bfloat16(f);
  return *reinterpret_cast<ushort*>(&h);
}
__device__ inline float b2f(ushort u) {
  union { float f; unsigned i; } x; x.i = ((unsigned)u) << 16; return x.f;
}
__device__ inline ushort f2h_(float f) {
  __half h = __float2half(f);
  return *reinterpret_cast<ushort*>(&h);
}
__device__ inline float h2f_(ushort u) {
  __half h = *reinterpret_cast<__half*>(&u);
  return __half2float(h);
}
__device__ inline const ushort* y2chunk_r(int blk, const ushort* rA, const ushort* rB,
                                          const ushort* rC) {
  if (blk < RA_CAP) return rA + (size_t)blk*CHUNK;
  if (blk < RA_CAP + RB_CAP) return rB + (size_t)(blk - RA_CAP)*CHUNK;
  return rC + (size_t)(blk - RA_CAP - RB_CAP)*CHUNK;
}
__device__ inline ushort* y2chunk_w(int blk, ushort* rA, ushort* rB, ushort* rC) {
  if (blk < RA_CAP) return rA + (size_t)blk*CHUNK;
  if (blk < RA_CAP + RB_CAP) return rB + (size_t)(blk - RA_CAP)*CHUNK;
  return rC + (size_t)(blk - RA_CAP - RB_CAP)*CHUNK;
}

// ---------------- f32 -> bf16 cast (8 elems/thread) ----------------
__global__ __launch_bounds__(256) void k_cast(const float* __restrict__ in,
                                              ushort* __restrict__ outp) {
  const int j = blockIdx.x*256 + threadIdx.x;       // 8-elem group
  float4 a = ((const float4*)in)[2*j];
  float4 b = ((const float4*)in)[2*j+1];
  ushort o[8] = { f2b(a.x), f2b(a.y), f2b(a.z), f2b(a.w),
                  f2b(b.x), f2b(b.y), f2b(b.z), f2b(b.w) };
  ((uint4*)outp)[j] = *(const uint4*)o;
}

// ---------------- bf16 MFMA GEMM: C = A[M,768] x B[N,768]^T ----------------
// EPI 0: qkv epilogue (RS scale q,k; bf16 scatter to [B,H,N,D]); EPI 1: +bias, f32 row-major
template<int EPI>
__global__ __launch_bounds__(256) void k_mfma_gemm(const ushort* __restrict__ A,
                                                   const ushort* __restrict__ B,
                                                   const float* __restrict__ bias,
                                                   void* __restrict__ o0,
                                                   void* __restrict__ o1,
                                                   void* __restrict__ o2) {
  __shared__ ushort As[128*72];
  __shared__ ushort Bs[128*72];
  const int t = threadIdx.x;
  const int m0 = blockIdx.y*128, n0 = blockIdx.x*128;
  const int w = t>>6, lane = t&63;
  const int wr = w>>1, wc = w&1;
  const int lrow = lane&15, lkb = lane>>4;
  f32x4 acc[4][4] = {};
  const int srow = t>>1, skoff = (t&1)*32;
  const ushort* aP = A + (size_t)(m0+srow)*768 + skoff;
  const ushort* bP = B + (size_t)(n0+srow)*768 + skoff;
  ushort* aw = &As[srow*72 + skoff];
  ushort* bw = &Bs[srow*72 + skoff];
  for (int k0 = 0; k0 < 768; k0 += 64) {
    uint4 a0 = *(const uint4*)(aP+k0),    a1 = *(const uint4*)(aP+k0+8);
    uint4 a2 = *(const uint4*)(aP+k0+16), a3 = *(const uint4*)(aP+k0+24);
    uint4 b0 = *(const uint4*)(bP+k0),    b1 = *(const uint4*)(bP+k0+8);
    uint4 b2 = *(const uint4*)(bP+k0+16), b3 = *(const uint4*)(bP+k0+24);
    __syncthreads();
    *(uint4*)(aw)    = a0; *(uint4*)(aw+8)  = a1;
    *(uint4*)(aw+16) = a2; *(uint4*)(aw+24) = a3;
    *(uint4*)(bw)    = b0; *(uint4*)(bw+8)  = b1;
    *(uint4*)(bw+16) = b2; *(uint4*)(bw+24) = b3;
    __syncthreads();
#pragma unroll
    for (int kk = 0; kk < 2; kk++) {
      bf16x8 af[4], bfr[4];
#pragma unroll
      for (int m = 0; m < 4; m++)
        af[m] = *(const bf16x8*)&As[(wr*64+m*16+lrow)*72 + kk*32 + lkb*8];
#pragma unroll
      for (int n = 0; n < 4; n++)
        bfr[n] = *(const bf16x8*)&Bs[(wc*64+n*16+lrow)*72 + kk*32 + lkb*8];
#pragma unroll
      for (int m = 0; m < 4; m++)
#pragma unroll
        for (int n = 0; n < 4; n++)
          acc[m][n] = __builtin_amdgcn_mfma_f32_16x16x32_bf16(af[m], bfr[n], acc[m][n], 0, 0, 0);
    }
  }
  const int r4 = lane>>4;
#pragma unroll
  for (int m = 0; m < 4; m++) {
#pragma unroll
    for (int r = 0; r < 4; r++) {
      const int grow = m0 + wr*64 + m*16 + r4*4 + r;
      if (EPI == 0) {
        ushort* q = (ushort*)o0; ushort* k = (ushort*)o1; ushort* v = (ushort*)o2;
        const int b = grow/196, nn = grow - b*196;
#pragma unroll
        for (int n = 0; n < 4; n++) {
          const int gcol = n0 + wc*64 + n*16 + lrow;
          const int three = gcol/768, rem = gcol - three*768;
          const int h = rem>>6, dd = rem&63;
          float val = acc[m][n][r] * (three < 2 ? RS : 1.0f);
          ushort* base = (three == 0) ? q : (three == 1) ? k : v;
          base[((size_t)(b*12+h)*196 + nn)*64 + dd] = f2b(val);
        }
      } else {
        float* outp = (float*)o0;
#pragma unroll
        for (int n = 0; n < 4; n++) {
          const int gcol = n0 + wc*64 + n*16 + lrow;
          outp[(size_t)grow*768 + gcol] = acc[m][n][r] + bias[gcol];
        }
      }
    }
  }
}

// ---------------- fused QK^T (MFMA) + register softmax -> attn f32 ----------------
// grid 1536 linear; XCD swizzle keeps the 4 slot-blocks of one bh on one XCD (K L2 reuse)
__global__ __launch_bounds__(256) void k_qks(const ushort* __restrict__ qb,
                                             const ushort* __restrict__ kb,
                                             float* __restrict__ attn) {
  __shared__ ushort K_lds[208*68];   // 28288 B
  const int t = threadIdx.x;
  const int lin = blockIdx.x;
  const int swz = (lin & 7)*192 + (lin >> 3);   // 1536 = 8*192, bijective
  const int bh = swz >> 2;
  const int sg = swz & 3;
  const ushort* kp = kb + (size_t)bh*Nn*Dd;
  const ushort* qp = qb + (size_t)bh*Nn*Dd;
  for (int i = t; i < 1568; i += 256) {
    int row = i >> 3, ko = (i & 7)*8;
    *(uint4*)&K_lds[row*68 + ko] = *(const uint4*)(kp + (size_t)row*64 + ko);
  }
  for (int i = t; i < 408; i += 256)
    ((unsigned*)&K_lds[196*68])[i] = 0u;
  __syncthreads();
  const int w = t >> 6, lane = t & 63;
  const int slot = sg*4 + w;               // m-tile 0..15 (13..15 idle)
  if (slot >= 13) return;
  const int lrow = lane & 15, lk = lane >> 4;
  int qrow = slot*16 + lrow; if (qrow > 195) qrow = 195;
  bf16x8 aq0 = *(const bf16x8*)(qp + (size_t)qrow*64 + lk*8);
  bf16x8 aq1 = *(const bf16x8*)(qp + (size_t)qrow*64 + 32 + lk*8);
  f32x4 acc[13];
#pragma unroll
  for (int nt = 0; nt < 13; nt++) {
    f32x4 a = {};
    bf16x8 b0 = *(const bf16x8*)&K_lds[(nt*16 + lrow)*68 + lk*8];
    a = __builtin_amdgcn_mfma_f32_16x16x32_bf16(aq0, b0, a, 0, 0, 0);
    bf16x8 b1 = *(const bf16x8*)&K_lds[(nt*16 + lrow)*68 + 32 + lk*8];
    acc[nt] = __builtin_amdgcn_mfma_f32_16x16x32_bf16(aq1, b1, a, 0, 0, 0);
  }
  const bool tailok = (lrow < 4);          // nt==12 valid cols: 192..195
  float inv[4];
#pragma unroll
  for (int r = 0; r < 4; r++) {
    float mx = -1e30f;
#pragma unroll
    for (int nt = 0; nt < 12; nt++) mx = fmaxf(mx, acc[nt][r]);
    if (tailok) mx = fmaxf(mx, acc[12][r]);
    mx = fmaxf(mx, __shfl_xor(mx, 1, 64));
    mx = fmaxf(mx, __shfl_xor(mx, 2, 64));
    mx = fmaxf(mx, __shfl_xor(mx, 4, 64));
    mx = fmaxf(mx, __shfl_xor(mx, 8, 64));
    float s = 0.0f;
#pragma unroll
    for (int nt = 0; nt < 13; nt++) {
      bool valid = (nt < 12) || tailok;
      float e = valid ? __expf(acc[nt][r] - mx) : 0.0f;
      acc[nt][r] = e;
      s += e;
    }
    s += __shfl_xor(s, 1, 64);
    s += __shfl_xor(s, 2, 64);
    s += __shfl_xor(s, 4, 64);
    s += __shfl_xor(s, 8, 64);
    inv[r] = 1.0f / s;
  }
  const int rowb = slot*16 + lk*4;
#pragma unroll
  for (int r = 0; r < 4; r++) {
    const int row = rowb + r;
    if (row < 196) {
      float* op = attn + ((size_t)bh*196 + row)*196;
#pragma unroll
      for (int nt = 0; nt < 13; nt++) {
        int col = nt*16 + lrow;
        if (col < 196) op[col] = acc[nt][r]*inv[r];
      }
    }
  }
}

// ---------------- Gram matrix M[h,h'] = sum attn_h * attn_h' (78 upper-tri) ----------------
__global__ __launch_bounds__(256) void k_gram(const float* __restrict__ attn,
                                              float* __restrict__ part) {
  __shared__ float red2[4*78];
  const int t = threadIdx.x;
  float m[78] = {};
  const int stride = gridDim.x * 256;
  const int NPAIR = SAMP/2;            // 614656
  for (int s = blockIdx.x*256 + t; s < NPAIR; s += stride) {
    int b = s / (NN2/2), p = (s - b*(NN2/2))*2;
    float2 a[12];
#pragma unroll
    for (int h = 0; h < 12; h++)
      a[h] = *(const float2*)&attn[((size_t)(b*12+h))*NN2 + p];
    int idx = 0;
#pragma unroll
    for (int h = 0; h < 12; h++)
#pragma unroll
      for (int h2 = h; h2 < 12; h2++, idx++) {
        m[idx] = fmaf(a[h].x, a[h2].x, m[idx]);
        m[idx] = fmaf(a[h].y, a[h2].y, m[idx]);
      }
  }
#pragma unroll
  for (int i = 0; i < 78; i++) {
#pragma unroll
    for (int off = 32; off; off >>= 1) m[i] += __shfl_xor(m[i], off, 64);
  }
  const int w = t >> 6;
  if ((t & 63) == 0) {
#pragma unroll
    for (int i = 0; i < 78; i++) red2[w*78 + i] = m[i];
  }
  __syncthreads();
  if (t < 78)
    part[(size_t)blockIdx.x*78 + t] = red2[t] + red2[78+t] + red2[156+t] + red2[234+t];
}

// ---------------- hierarchical deterministic reduce ----------------
__global__ __launch_bounds__(256) void k_reduce(const float* __restrict__ part, int nb,
                                               int stride, double* __restrict__ dsum) {
  __shared__ double sh[256];
  const int c = blockIdx.x;
  const int t = threadIdx.x;
  double s = 0.0;
  for (int i = t; i < nb; i += 256) s += (double)part[(size_t)i*stride + c];
  sh[t] = s;
  __syncthreads();
  for (int o = 128; o; o >>= 1) {
    if (t < o) sh[t] += sh[t + o];
    __syncthreads();
  }
  if (t == 0) dsum[c] = sh[0];
}

// ---------------- bn1 affine from Gram (dsum[78]) ----------------
__global__ void k_bn1gram(const double* __restrict__ dsum,
                          const float* __restrict__ w_exp,
                          const float* __restrict__ g, const float* __restrict__ beta,
                          float* __restrict__ stats) {
  int c = threadIdx.x;
  if (c >= 36) return;
  float wv[12];
  float mean = 0.0f;
#pragma unroll
  for (int h = 0; h < 12; h++) { wv[h] = w_exp[c*12+h]; mean += wv[h]; }
  mean *= (1.0f/196.0f);
  double e2 = 0.0;
  int idx = 0;
#pragma unroll
  for (int h = 0; h < 12; h++)
#pragma unroll
    for (int h2 = h; h2 < 12; h2++, idx++) {
      double coef = (double)wv[h] * (double)wv[h2] * (h == h2 ? 1.0 : 2.0);
      e2 += coef * dsum[idx];
    }
  double var = e2 / (double)SAMP - (double)mean*mean;
  float a = g[c] * rsqrtf((float)var + 1e-5f);
  stats[c] = a;
  stats[36 + c] = beta[c] - mean * a;
}

// ---- pass A: expand (halo, 256 thr) + column-sweep dw, 2 groups of 18 ch
//      XCD-swizzled blocks: each XCD walks 784 consecutive tiles (4 batches, L2-resident attn)
__global__ __launch_bounds__(256) void k_dlaA(const float* __restrict__ attn,
                                              const float* __restrict__ w_exp,
                                              const float* __restrict__ w_dw,
                                              const float* __restrict__ stats,
                                              ushort* __restrict__ rA,
                                              ushort* __restrict__ rB,
                                              ushort* __restrict__ rC,
                                              float* __restrict__ part) {
  __shared__ float  y_s[18*263];    // stride 263 (mod32=7)
  __shared__ ushort y2l[18*200];    // y2 fp16 transpose-staging
  __shared__ float  sbuf[2*252];    // per-(cl,col) s1/s2 partials
  const int t = threadIdx.x;
  const int bid = blockIdx.x;
  const int blk = (bid & 7)*784 + (bid >> 3);   // 6272 = 8*784, bijective XCD swizzle
  const int b = blk / 196, tile = blk - b*196;
  const int tyq = tile / 14;
  const int ty0 = tyq * 14, tx0 = (tile - tyq*14) * 14;
  const int hy = ty0 + (t >> 4) - 1, hx = tx0 + (t & 15) - 1;
  const bool inb = (hy >= 0) && (hy < 196) && (hx >= 0) && (hx < 196);
  float a[12];
#pragma unroll
  for (int ch = 0; ch < 12; ch++)
    a[ch] = inb ? attn[((size_t)(b*12+ch))*NN2 + (size_t)hy*196 + hx] : 0.0f;

  const bool dwact = (t < 252);
  const int cl = t % 18, col = t / 18;      // dw role: channel-in-group, output column
  ushort* ydst = (blk < NCACHE) ? y2chunk_w(blk, rA, rB, rC) : nullptr;

  for (int g = 0; g < 2; g++) {
    __syncthreads();
#pragma unroll
    for (int c2 = 0; c2 < 18; c2++) {
      const int c = g*18 + c2;
      float y = 0.0f;
#pragma unroll
      for (int h = 0; h < 12; h++) y = fmaf(w_exp[c*12+h], a[h], y);
      y = y*stats[c] + stats[36+c];
      y = fminf(fmaxf(y, 0.0f), 6.0f);
      y_s[c2*263 + t] = inb ? y : 0.0f;
    }
    __syncthreads();
    if (dwact) {
      const int c = g*18 + cl;
      const float* ys = &y_s[cl*263 + col];
      const float* wd = &w_dw[c*9];
      float s1 = 0.0f, s2 = 0.0f;
      ushort y2h[14];
      float r0c0 = ys[0],  r0c1 = ys[1],  r0c2 = ys[2];
      float r1c0 = ys[16], r1c1 = ys[17], r1c2 = ys[18];
#pragma unroll
      for (int r = 0; r < 14; r++) {
        float r2c0 = ys[(r+2)*16], r2c1 = ys[(r+2)*16+1], r2c2 = ys[(r+2)*16+2];
        float y2 = wd[0]*r0c0;
        y2 = fmaf(wd[1], r0c1, y2); y2 = fmaf(wd[2], r0c2, y2);
        y2 = fmaf(wd[3], r1c0, y2); y2 = fmaf(wd[4], r1c1, y2);
        y2 = fmaf(wd[5], r1c2, y2); y2 = fmaf(wd[6], r2c0, y2);
        y2 = fmaf(wd[7], r2c1, y2); y2 = fmaf(wd[8], r2c2, y2);
        s1 += y2; s2 = fmaf(y2, y2, s2);
        y2h[r] = f2h_(y2);
        r0c0 = r1c0; r0c1 = r1c1; r0c2 = r1c2;
        r1c0 = r2c0; r1c1 = r2c1; r1c2 = r2c2;
      }
      sbuf[cl*14 + col] = s1;
      sbuf[252 + cl*14 + col] = s2;
#pragma unroll
      for (int r = 0; r < 14; r++) y2l[cl*200 + r*14 + col] = y2h[r];
    }
    __syncthreads();
    if (ydst) {
      // vectorized readout: 882 uint2 groups (4 ushorts each), 18 ch x 196 px
      for (int i = t; i < 882; i += 256) {
        int c2 = i / 49, q = i - c2*49;
        uint2 v = *(const uint2*)&y2l[c2*200 + q*4];
        *(uint2*)&ydst[g*3528 + c2*196 + q*4] = v;
      }
    }
    if (t < 36) {
      const int cc = t % 18, wh = t / 18;
      float s = 0.0f;
#pragma unroll
      for (int j = 0; j < 14; j++) s += sbuf[wh*252 + cc*14 + j];
      part[(size_t)blk*72 + wh*36 + g*18 + cc] = s;
    }
  }
}

// ---- pass B light: one pixel-pair per thread, 2 chunks per block (grid 3038) ----
__global__ __launch_bounds__(256) void k_dlaBlight(const ushort* __restrict__ rA,
                                                   const ushort* __restrict__ rB,
                                                   const ushort* __restrict__ rC,
                                                   const float* __restrict__ w_pro,
                                                   const float* __restrict__ stats,
                                                   float* __restrict__ zatt,
                                                   float* __restrict__ part) {
  __shared__ float red[4*24];
  const int t = threadIdx.x;
  const int blk = blockIdx.x;            // [0, NLB)
  const bool act = (t < 196);
  float s1[12] = {}, s2[12] = {};
  if (act) {
    const int chunk = blk*2 + (t / 98);  // [0, NCACHE)
    const int j = t % 98;                // pair index within chunk
    const int b = chunk / 196, tile = chunk - b*196;
    const int tyq = tile / 14;
    const int ty0 = tyq*14, tx0 = (tile - tyq*14)*14;
    const int p = 2*j;
    const int r = p / 14, cx = p - r*14; // 14 even -> pair stays in one row
    const ushort* src = y2chunk_r(chunk, rA, rB, rC) + p;
    float z0[12] = {}, z1[12] = {};
#pragma unroll
    for (int c = 0; c < 36; c++) {
      const unsigned u = *(const unsigned*)(src + c*196);
      float ya = h2f_((ushort)(u & 0xffffu));
      float yb = h2f_((ushort)(u >> 16));
      const float A2 = stats[72+c], B2 = stats[108+c];
      ya = fminf(fmaxf(fmaf(ya, A2, B2), 0.0f), 6.0f);
      yb = fminf(fmaxf(fmaf(yb, A2, B2), 0.0f), 6.0f);
#pragma unroll
      for (int cc = 0; cc < 12; cc++) {
        const float wp = w_pro[cc*36 + c];
        z0[cc] = fmaf(wp, ya, z0[cc]);
        z1[cc] = fmaf(wp, yb, z1[cc]);
      }
    }
    const int oy = ty0 + r, ox = tx0 + cx;
#pragma unroll
    for (int cc = 0; cc < 12; cc++) {
      *(float2*)&zatt[((size_t)(b*12+cc))*NN2 + (size_t)oy*196 + ox] =
          make_float2(z0[cc], z1[cc]);
      s1[cc] = z0[cc] + z1[cc];
      s2[cc] = z0[cc]*z0[cc] + z1[cc]*z1[cc];
    }
  }
#pragma unroll
  for (int cc = 0; cc < 12; cc++) {
#pragma unroll
    for (int off = 32; off; off >>= 1) {
      s1[cc] += __shfl_xor(s1[cc], off, 64);
      s2[cc] += __shfl_xor(s2[cc], off, 64);
    }
  }
  const int w = t >> 6;
  if ((t & 63) == 0) {
#pragma unroll
    for (int cc = 0; cc < 12; cc++) {
      red[w*24 + cc] = s1[cc];
      red[w*24 + 12 + cc] = s2[cc];
    }
  }
  __syncthreads();
  if (t < 24)
    part[(size_t)blk*24 + t] = red[t] + red[24+t] + red[48+t] + red[72+t];
}

// ---- pass B heavy: batch-31 full recompute (196 blocks); part rows NLB.. ----
__global__ __launch_bounds__(256) void k_dlaBheavy(const float* __restrict__ attn,
                                                   const float* __restrict__ w_exp,
                                                   const float* __restrict__ w_dw,
                                                   const float* __restrict__ w_pro,
                                                   const float* __restrict__ stats,
                                                   float* __restrict__ z31,
                                                   float* __restrict__ part) {
  __shared__ float y_s[12*256];
  __shared__ float z2[12*200];
  const int t = threadIdx.x;
  const int tile = blockIdx.x;
  const int b = 31;
  const int tyq = tile / 14;
  const int ty0 = tyq * 14, tx0 = (tile - tyq*14) * 14;
  const bool act = (t < 196);
  const int py = t / 14, px = t - py*14;
  const int oy = ty0 + py, ox = tx0 + px;
  float z[12] = {};
  const int hy = ty0 + (t >> 4) - 1, hx = tx0 + (t & 15) - 1;
  const bool inb = (hy >= 0) && (hy < 196) && (hx >= 0) && (hx < 196);
  float a[12];
#pragma unroll
  for (int ch = 0; ch < 12; ch++)
    a[ch] = inb ? attn[((size_t)(b*12+ch))*NN2 + (size_t)hy*196 + hx] : 0.0f;
  const int base = (py+1)*16 + (px+1);
  for (int g = 0; g < 3; g++) {
    __syncthreads();
#pragma unroll
    for (int cl = 0; cl < 12; cl++) {
      const int c = g*12 + cl;
      float y = 0.0f;
#pragma unroll
      for (int h = 0; h < 12; h++) y = fmaf(w_exp[c*12+h], a[h], y);
      y = y*stats[c] + stats[36+c];
      y = fminf(fmaxf(y, 0.0f), 6.0f);
      y_s[cl*256 + t] = inb ? y : 0.0f;
    }
    __syncthreads();
    if (act) {
#pragma unroll
      for (int cl = 0; cl < 12; cl++) {
        const int c = g*12 + cl;
        const float* ys = &y_s[cl*256];
        float y2 = 0.0f;
#pragma unroll
        for (int di = 0; di < 3; di++)
#pragma unroll
          for (int dj = 0; dj < 3; dj++)
            y2 = fmaf(w_dw[c*9 + di*3 + dj], ys[base + (di-1)*16 + (dj-1)], y2);
        float y2c = y2*stats[72+c] + stats[108+c];
        y2c = fminf(fmaxf(y2c, 0.0f), 6.0f);
#pragma unroll
        for (int cc = 0; cc < 12; cc++) z[cc] = fmaf(w_pro[cc*36+c], y2c, z[cc]);
      }
    }
  }
  if (act) {
#pragma unroll
    for (int cc = 0; cc < 12; cc++)
      z31[(size_t)cc*NN2 + (size_t)oy*196 + ox] = z[cc];
  }
  // z stats
  __syncthreads();
  if (act) {
#pragma unroll
    for (int cc = 0; cc < 12; cc++) z2[cc*200 + t] = z[cc];
  }
  __syncthreads();
  const int rs = t >> 3, seg = t & 7;
  const int pix0 = seg*25;
  const int pcnt = (seg == 7) ? 21 : 25;
  if (rs < 24) {
    const int cl = rs % 12, wh = rs / 12;
    float s = 0.0f;
    for (int i = 0; i < pcnt; i++) {
      float v = z2[cl*200 + pix0 + i];
      s += wh ? v*v : v;
    }
    s += __shfl_xor(s, 1, 64);
    s += __shfl_xor(s, 2, 64);
    s += __shfl_xor(s, 4, 64);
    if (seg == 0)
      part[(size_t)(NLB + tile)*24 + wh*12 + cl] = s;
  }
}

// ---------------- dsum -> BN affine (36 ch, bn2) ----------------
__global__ void k_bnaffine36(const double* __restrict__ dsum,
                             const float* __restrict__ g, const float* __restrict__ beta,
                             float* __restrict__ stats, int off) {
  int c = threadIdx.x;
  if (c >= 36) return;
  double m = dsum[c] / (double)SAMP;
  double v = dsum[36 + c] / (double)SAMP - m*m;
  float a = g[c] * rsqrtf((float)v + 1e-5f);
  stats[off + c] = a;
  stats[off + 36 + c] = beta[c] - (float)m * a;
}

// ---------------- combined bn3 + adapt_bn affine (from dsum[24]) ----------------
__global__ void k_bnfinal(const double* __restrict__ dsum,
                          const float* __restrict__ g3, const float* __restrict__ b3,
                          const float* __restrict__ ag, const float* __restrict__ ab,
                          float* __restrict__ stats) {
  int c = threadIdx.x;
  if (c >= 12) return;
  (void)b3;
  double m = dsum[c] / (double)SAMP;
  double v = dsum[12 + c] / (double)SAMP - m*m;
  float r1 = rsqrtf((float)v + 1e-5f);
  float vt = g3[c]*g3[c]*(float)v*r1*r1;
  float r2 = rsqrtf(vt + 1e-5f);
  float A = g3[c]*ag[c]*r1*r2;
  stats[144 + c] = A;
  stats[156 + c] = ab[c] - (float)m*A;
}

// ---------------- V transpose: v16 [BH][196][64] -> vt [BH][64][224] bf16 (zero-pad) ----------------
__global__ __launch_bounds__(256) void k_vt(const ushort* __restrict__ v16,
                                            ushort* __restrict__ vt) {
  __shared__ ushort Vl[196*68];
  const int t = threadIdx.x, bh = blockIdx.x;
  const ushort* vp = v16 + (size_t)bh*Nn*Dd;
  for (int i = t; i < 1568; i += 256) {
    int row = i >> 3, ko = (i & 7)*8;
    *(uint4*)&Vl[row*68 + ko] = *(const uint4*)(vp + (size_t)row*64 + ko);
  }
  __syncthreads();
  ushort* dst = vt + (size_t)bh*64*224;
  for (int i = t; i < 64*28; i += 256) {
    int d = i / 28, q = i - d*28;
    ushort tmp[8];
#pragma unroll
    for (int j = 0; j < 8; j++) {
      int m = q*8 + j;
      tmp[j] = (m < 196) ? Vl[m*68 + d] : (ushort)0;
    }
    *(uint4*)&dst[d*224 + q*8] = *(const uint4*)tmp;
  }
}

// ---------------- MFMA PV: attn_r = z*Af+Bf (f32, in-place for b<31), O = P@Vt -> out_pre bf16 ----------------
__global__ __launch_bounds__(256) void k_pvm(const float* __restrict__ z31,
                                             const ushort* __restrict__ vt,
                                             const float* __restrict__ stats,
                                             float* __restrict__ attn_r,
                                             ushort* __restrict__ out_pre) {
  constexpr int STR = 232;
  __shared__ ushort U[32*STR];         // 14848 B: P tile only
  const int t = threadIdx.x;
  const int bh = blockIdx.x;
  const int r0 = blockIdx.y * 32;
  const int b = bh / 12, h = bh - b*12;
  const float Af = stats[144 + h], Bf = stats[156 + h];
  for (int i = t; i < 32*STR/8; i += 256)
    ((uint4*)U)[i] = make_uint4(0,0,0,0);
  __syncthreads();
  const int nvalid = (r0 + 32 <= 196) ? 32 : (196 - r0);
  float* arp = attn_r + (size_t)bh*NN2 + (size_t)r0*196;
  const float* zp = (b < 31) ? arp : (z31 + (size_t)h*NN2 + (size_t)r0*196);
  for (int idx = t; idx < nvalid*196; idx += 256) {
    int rr = idx / 196, m = idx - rr*196;
    float val = fmaf(zp[(size_t)rr*196 + m], Af, Bf);
    arp[(size_t)rr*196 + m] = val;
    U[rr*STR + m] = f2b(val);
  }
  __syncthreads();
  const int w = t >> 6, lane = t & 63;
  const int mt = w >> 1, ct = w & 1;
  const int lr = lane & 15, lk = lane >> 4;
  const ushort* vbase = vt + (size_t)bh*64*224;
#pragma unroll
  for (int cn = 0; cn < 2; cn++) {
    const int n0 = ct*32 + cn*16;
    f32x4 acc = {};
#pragma unroll
    for (int ks = 0; ks < 7; ks++) {
      bf16x8 af = *(const bf16x8*)&U[(mt*16 + lr)*STR + ks*32 + lk*8];
      bf16x8 bf = *(const bf16x8*)&vbase[(size_t)(n0 + lr)*224 + ks*32 + lk*8];
      acc = __builtin_amdgcn_mfma_f32_16x16x32_bf16(af, bf, acc, 0, 0, 0);
    }
#pragma unroll
    for (int r = 0; r < 4; r++) {
      int row = mt*16 + lk*4 + r;
      if (row < nvalid)
        out_pre[((size_t)(b*196 + r0 + row))*Cc + h*64 + n0 + lr] = f2b(acc[r]);
    }
  }
}

// ---------------- launch ----------------
extern "C" void kernel_launch(void* const* d_in, const int* in_sizes, int n_in,
                              void* d_out, int out_size, void* d_ws, size_t ws_size,
                              hipStream_t stream) {
  (void)in_sizes; (void)n_in; (void)out_size; (void)ws_size;
  const float* x      = (const float*)d_in[0];
  const float* w_qkv  = (const float*)d_in[1];
  const float* w_exp  = (const float*)d_in[2];
  const float* bn1_g  = (const float*)d_in[3];
  const float* bn1_b  = (const float*)d_in[4];
  const float* w_dw   = (const float*)d_in[5];
  const float* bn2_g  = (const float*)d_in[6];
  const float* bn2_b  = (const float*)d_in[7];
  const float* w_pro  = (const float*)d_in[8];
  const float* bn3_g  = (const float*)d_in[9];
  const float* bn3_b  = (const float*)d_in[10];
  const float* abn_g  = (const float*)d_in[11];
  const float* abn_b  = (const float*)d_in[12];
  const float* w_proj = (const float*)d_in[13];
  const float* b_proj = (const float*)d_in[14];

  float* out      = (float*)d_out;
  float* attn_out = out + (size_t)QSZ;      // d_out attn region: attn -> z(b<31) -> attn_r
  float* ws    = (float*)d_ws;
  ushort* vb16 = (ushort*)ws;               // [QSZ ushorts]
  ushort* opb  = (ushort*)ws + (size_t)QSZ; // [QSZ ushorts]: y2 cache rC -> out_pre
  float*  big  = ws + (size_t)QSZ;          // [ATT]: {q,k bf16} -> y2 cache rA
  ushort* qb16 = (ushort*)big;
  ushort* kb16 = qb16 + (size_t)QSZ;
  float* stats = ws + (size_t)QSZ + ATT;    // [256]
  float* part  = stats + 256;               // [6272*72]
  double* dsum = (double*)(part + (size_t)6272*72); // [96]
  float* z31   = (float*)(dsum + 96);       // [12*NN2] batch-31 z aux

  // staging in dead d_out region:
  ushort* xb   = (ushort*)out;              // x bf16
  ushort* wqb  = xb + (size_t)QSZ;          // w_qkv bf16
  ushort* rB   = (ushort*)out;              // y2 cache region B (after gemm<0> consumed xb/wqb)
  ushort* vtb  = (ushort*)out;              // V^T [384][64][224] (after rB consumed by dlaBlight)
  ushort* wpb  = (ushort*)part;             // w_proj bf16 (part dead after last reduce)

  k_cast <<<QSZ/2048, 256, 0, stream>>>(x, xb);
  k_cast <<<(2304*768)/2048, 256, 0, stream>>>(w_qkv, wqb);
  k_mfma_gemm<0><<<dim3(18, 49), 256, 0, stream>>>(xb, wqb, nullptr, qb16, kb16, vb16);
  k_qks      <<<1536, 256, 0, stream>>>(qb16, kb16, attn_out);
  k_gram     <<<2048, 256, 0, stream>>>(attn_out, part);
  k_reduce   <<<78, 256, 0, stream>>>(part, 2048, 78, dsum);
  k_bn1gram  <<<1, 64, 0, stream>>>(dsum, w_exp, bn1_g, bn1_b, stats);
  k_dlaA     <<<6272, 256, 0, stream>>>(attn_out, w_exp, w_dw, stats,
                                        (ushort*)big, rB, opb, part);
  k_reduce   <<<72, 256, 0, stream>>>(part, 6272, 72, dsum);
  k_bnaffine36<<<1, 64, 0, stream>>>(dsum, bn2_g, bn2_b, stats, 72);
  k_dlaBlight<<<NLB, 256, 0, stream>>>((const ushort*)big, rB, opb, w_pro, stats,
                                       attn_out, part);
  k_dlaBheavy<<<196, 256, 0, stream>>>(attn_out, w_exp, w_dw, w_pro, stats, z31, part);
  k_reduce   <<<24, 256, 0, stream>>>(part, NLB + 196, 24, dsum);
  k_bnfinal  <<<1, 64, 0, stream>>>(dsum, bn3_g, bn3_b, abn_g, abn_b, stats);
  k_vt       <<<384, 256, 0, stream>>>(vb16, vtb);                           // rB dead now
  k_cast     <<<(768*768)/2048, 256, 0, stream>>>(w_proj, wpb);
  k_pvm      <<<dim3(384, 7), 256, 0, stream>>>(z31, vtb, stats, attn_out, opb);
  k_mfma_gemm<1><<<dim3(6, 49), 256, 0, stream>>>(opb, wpb, b_proj, out, nullptr, nullptr);
}

// Round 19
// 329.093 us; speedup vs baseline: 1.0284x; 1.0050x over previous
//
#include <hip/hip_runtime.h>
#include <hip/hip_bf16.h>
#include <hip/hip_fp16.h>
#include <math.h>

// ---------------- problem constants ----------------
constexpr int Bz  = 32;
constexpr int Nn  = 196;
constexpr int Cc  = 768;
constexpr int Hh  = 12;
constexpr int Dd  = 64;
constexpr int NN2 = Nn * Nn;      // 38416
constexpr int QSZ = Bz * Nn * Cc;          // 4,816,896
constexpr int ATT = Bz * Hh * NN2;         // 14,751,744
constexpr int SAMP = Bz * NN2;    // 1,229,312 samples per BN channel
constexpr float RS = 0.35355339059327373f; // 64^-0.25
// y2 cache geometry: 36*196 = 7056 fp16 per block; blocks 0..6075 cached (batches 0..30)
constexpr int CHUNK = 7056;
constexpr int NCACHE = 6076;      // 31 batches * 196 tiles
constexpr int RA_CAP = 4181;      // chunks in big region
constexpr int RB_CAP = 1365;      // chunks in d_out[0..QSZ) region
constexpr int NLB = NCACHE/2;     // 3038 light-B blocks

typedef short bf16x8 __attribute__((ext_vector_type(8)));
typedef float f32x4  __attribute__((ext_vector_type(4)));

__device__ inline ushort f2b(float f) {
  __hip_bfloat16 h = __float2bfloat16(f);
  return *reinterpret_cast<ushort*>(&h);
}
__device__ inline float b2f(ushort u) {
  union { float f; unsigned i; } x; x.i = ((unsigned)u) << 16; return x.f;
}
__device__ inline ushort f2h_(float f) {
  __half h = __float2half(f);
  return *reinterpret_cast<ushort*>(&h);
}
__device__ inline float h2f_(ushort u) {
  __half h = *reinterpret_cast<__half*>(&u);
  return __half2float(h);
}
__device__ inline const ushort* y2chunk_r(int blk, const ushort* rA, const ushort* rB,
                                          const ushort* rC) {
  if (blk < RA_CAP) return rA + (size_t)blk*CHUNK;
  if (blk < RA_CAP + RB_CAP) return rB + (size_t)(blk - RA_CAP)*CHUNK;
  return rC + (size_t)(blk - RA_CAP - RB_CAP)*CHUNK;
}
__device__ inline ushort* y2chunk_w(int blk, ushort* rA, ushort* rB, ushort* rC) {
  if (blk < RA_CAP) return rA + (size_t)blk*CHUNK;
  if (blk < RA_CAP + RB_CAP) return rB + (size_t)(blk - RA_CAP)*CHUNK;
  return rC + (size_t)(blk - RA_CAP - RB_CAP)*CHUNK;
}

// ---------------- f32 -> bf16 cast (8 elems/thread) ----------------
__global__ __launch_bounds__(256) void k_cast(const float* __restrict__ in,
                                              ushort* __restrict__ outp) {
  const int j = blockIdx.x*256 + threadIdx.x;       // 8-elem group
  float4 a = ((const float4*)in)[2*j];
  float4 b = ((const float4*)in)[2*j+1];
  ushort o[8] = { f2b(a.x), f2b(a.y), f2b(a.z), f2b(a.w),
                  f2b(b.x), f2b(b.y), f2b(b.z), f2b(b.w) };
  ((uint4*)outp)[j] = *(const uint4*)o;
}

// ---------------- bf16 MFMA GEMM: C = A[M,768] x B[N,768]^T ----------------
// EPI 0: qkv epilogue (RS scale q,k; bf16 scatter to [B,H,N,D]); EPI 1: +bias, f32 row-major
template<int EPI>
__global__ __launch_bounds__(256) void k_mfma_gemm(const ushort* __restrict__ A,
                                                   const ushort* __restrict__ B,
                                                   const float* __restrict__ bias,
                                                   void* __restrict__ o0,
                                                   void* __restrict__ o1,
                                                   void* __restrict__ o2) {
  __shared__ ushort As[128*72];
  __shared__ ushort Bs[128*72];
  const int t = threadIdx.x;
  const int m0 = blockIdx.y*128, n0 = blockIdx.x*128;
  const int w = t>>6, lane = t&63;
  const int wr = w>>1, wc = w&1;
  const int lrow = lane&15, lkb = lane>>4;
  f32x4 acc[4][4] = {};
  const int srow = t>>1, skoff = (t&1)*32;
  const ushort* aP = A + (size_t)(m0+srow)*768 + skoff;
  const ushort* bP = B + (size_t)(n0+srow)*768 + skoff;
  ushort* aw = &As[srow*72 + skoff];
  ushort* bw = &Bs[srow*72 + skoff];
  for (int k0 = 0; k0 < 768; k0 += 64) {
    uint4 a0 = *(const uint4*)(aP+k0),    a1 = *(const uint4*)(aP+k0+8);
    uint4 a2 = *(const uint4*)(aP+k0+16), a3 = *(const uint4*)(aP+k0+24);
    uint4 b0 = *(const uint4*)(bP+k0),    b1 = *(const uint4*)(bP+k0+8);
    uint4 b2 = *(const uint4*)(bP+k0+16), b3 = *(const uint4*)(bP+k0+24);
    __syncthreads();
    *(uint4*)(aw)    = a0; *(uint4*)(aw+8)  = a1;
    *(uint4*)(aw+16) = a2; *(uint4*)(aw+24) = a3;
    *(uint4*)(bw)    = b0; *(uint4*)(bw+8)  = b1;
    *(uint4*)(bw+16) = b2; *(uint4*)(bw+24) = b3;
    __syncthreads();
#pragma unroll
    for (int kk = 0; kk < 2; kk++) {
      bf16x8 af[4], bfr[4];
#pragma unroll
      for (int m = 0; m < 4; m++)
        af[m] = *(const bf16x8*)&As[(wr*64+m*16+lrow)*72 + kk*32 + lkb*8];
#pragma unroll
      for (int n = 0; n < 4; n++)
        bfr[n] = *(const bf16x8*)&Bs[(wc*64+n*16+lrow)*72 + kk*32 + lkb*8];
#pragma unroll
      for (int m = 0; m < 4; m++)
#pragma unroll
        for (int n = 0; n < 4; n++)
          acc[m][n] = __builtin_amdgcn_mfma_f32_16x16x32_bf16(af[m], bfr[n], acc[m][n], 0, 0, 0);
    }
  }
  const int r4 = lane>>4;
#pragma unroll
  for (int m = 0; m < 4; m++) {
#pragma unroll
    for (int r = 0; r < 4; r++) {
      const int grow = m0 + wr*64 + m*16 + r4*4 + r;
      if (EPI == 0) {
        ushort* q = (ushort*)o0; ushort* k = (ushort*)o1; ushort* v = (ushort*)o2;
        const int b = grow/196, nn = grow - b*196;
#pragma unroll
        for (int n = 0; n < 4; n++) {
          const int gcol = n0 + wc*64 + n*16 + lrow;
          const int three = gcol/768, rem = gcol - three*768;
          const int h = rem>>6, dd = rem&63;
          float val = acc[m][n][r] * (three < 2 ? RS : 1.0f);
          ushort* base = (three == 0) ? q : (three == 1) ? k : v;
          base[((size_t)(b*12+h)*196 + nn)*64 + dd] = f2b(val);
        }
      } else {
        float* outp = (float*)o0;
#pragma unroll
        for (int n = 0; n < 4; n++) {
          const int gcol = n0 + wc*64 + n*16 + lrow;
          outp[(size_t)grow*768 + gcol] = acc[m][n][r] + bias[gcol];
        }
      }
    }
  }
}

// ---------------- fused QK^T (MFMA) + register softmax -> attn bf16 ----------------
// grid 1536 linear; XCD swizzle keeps the 4 slot-blocks of one bh on one XCD (K L2 reuse)
__global__ __launch_bounds__(256) void k_qks(const ushort* __restrict__ qb,
                                             const ushort* __restrict__ kb,
                                             ushort* __restrict__ attn) {
  __shared__ ushort K_lds[208*68];   // 28288 B
  const int t = threadIdx.x;
  const int lin = blockIdx.x;
  const int swz = (lin & 7)*192 + (lin >> 3);   // 1536 = 8*192, bijective
  const int bh = swz >> 2;
  const int sg = swz & 3;
  const ushort* kp = kb + (size_t)bh*Nn*Dd;
  const ushort* qp = qb + (size_t)bh*Nn*Dd;
  for (int i = t; i < 1568; i += 256) {
    int row = i >> 3, ko = (i & 7)*8;
    *(uint4*)&K_lds[row*68 + ko] = *(const uint4*)(kp + (size_t)row*64 + ko);
  }
  for (int i = t; i < 408; i += 256)
    ((unsigned*)&K_lds[196*68])[i] = 0u;
  __syncthreads();
  const int w = t >> 6, lane = t & 63;
  const int slot = sg*4 + w;               // m-tile 0..15 (13..15 idle)
  if (slot >= 13) return;
  const int lrow = lane & 15, lk = lane >> 4;
  int qrow = slot*16 + lrow; if (qrow > 195) qrow = 195;
  bf16x8 aq0 = *(const bf16x8*)(qp + (size_t)qrow*64 + lk*8);
  bf16x8 aq1 = *(const bf16x8*)(qp + (size_t)qrow*64 + 32 + lk*8);
  f32x4 acc[13];
#pragma unroll
  for (int nt = 0; nt < 13; nt++) {
    f32x4 a = {};
    bf16x8 b0 = *(const bf16x8*)&K_lds[(nt*16 + lrow)*68 + lk*8];
    a = __builtin_amdgcn_mfma_f32_16x16x32_bf16(aq0, b0, a, 0, 0, 0);
    bf16x8 b1 = *(const bf16x8*)&K_lds[(nt*16 + lrow)*68 + 32 + lk*8];
    acc[nt] = __builtin_amdgcn_mfma_f32_16x16x32_bf16(aq1, b1, a, 0, 0, 0);
  }
  const bool tailok = (lrow < 4);          // nt==12 valid cols: 192..195
  float inv[4];
#pragma unroll
  for (int r = 0; r < 4; r++) {
    float mx = -1e30f;
#pragma unroll
    for (int nt = 0; nt < 12; nt++) mx = fmaxf(mx, acc[nt][r]);
    if (tailok) mx = fmaxf(mx, acc[12][r]);
    mx = fmaxf(mx, __shfl_xor(mx, 1, 64));
    mx = fmaxf(mx, __shfl_xor(mx, 2, 64));
    mx = fmaxf(mx, __shfl_xor(mx, 4, 64));
    mx = fmaxf(mx, __shfl_xor(mx, 8, 64));
    float s = 0.0f;
#pragma unroll
    for (int nt = 0; nt < 13; nt++) {
      bool valid = (nt < 12) || tailok;
      float e = valid ? __expf(acc[nt][r] - mx) : 0.0f;
      acc[nt][r] = e;
      s += e;
    }
    s += __shfl_xor(s, 1, 64);
    s += __shfl_xor(s, 2, 64);
    s += __shfl_xor(s, 4, 64);
    s += __shfl_xor(s, 8, 64);
    inv[r] = 1.0f / s;
  }
  const int rowb = slot*16 + lk*4;
#pragma unroll
  for (int r = 0; r < 4; r++) {
    const int row = rowb + r;
    if (row < 196) {
      ushort* op = attn + ((size_t)bh*196 + row)*196;
#pragma unroll
      for (int nt = 0; nt < 13; nt++) {
        int col = nt*16 + lrow;
        if (col < 196) op[col] = f2b(acc[nt][r]*inv[r]);
      }
    }
  }
}

// ---------------- Gram matrix M[h,h'] = sum attn_h * attn_h' (78 upper-tri), bf16 pairs ----------------
__global__ __launch_bounds__(256) void k_gram(const ushort* __restrict__ attn,
                                              float* __restrict__ part) {
  __shared__ float red2[4*78];
  const int t = threadIdx.x;
  float m[78] = {};
  const int stride = gridDim.x * 256;
  const int NPAIR = SAMP/2;            // 614656
  for (int s = blockIdx.x*256 + t; s < NPAIR; s += stride) {
    int b = s / (NN2/2), p = (s - b*(NN2/2))*2;
    float ax[12], ay[12];
#pragma unroll
    for (int h = 0; h < 12; h++) {
      unsigned u = *(const unsigned*)&attn[((size_t)(b*12+h))*NN2 + p];
      ax[h] = b2f((ushort)(u & 0xffffu));
      ay[h] = b2f((ushort)(u >> 16));
    }
    int idx = 0;
#pragma unroll
    for (int h = 0; h < 12; h++)
#pragma unroll
      for (int h2 = h; h2 < 12; h2++, idx++) {
        m[idx] = fmaf(ax[h], ax[h2], m[idx]);
        m[idx] = fmaf(ay[h], ay[h2], m[idx]);
      }
  }
#pragma unroll
  for (int i = 0; i < 78; i++) {
#pragma unroll
    for (int off = 32; off; off >>= 1) m[i] += __shfl_xor(m[i], off, 64);
  }
  const int w = t >> 6;
  if ((t & 63) == 0) {
#pragma unroll
    for (int i = 0; i < 78; i++) red2[w*78 + i] = m[i];
  }
  __syncthreads();
  if (t < 78)
    part[(size_t)blockIdx.x*78 + t] = red2[t] + red2[78+t] + red2[156+t] + red2[234+t];
}

// ---------------- hierarchical deterministic reduce ----------------
__global__ __launch_bounds__(256) void k_reduce(const float* __restrict__ part, int nb,
                                               int stride, double* __restrict__ dsum) {
  __shared__ double sh[256];
  const int c = blockIdx.x;
  const int t = threadIdx.x;
  double s = 0.0;
  for (int i = t; i < nb; i += 256) s += (double)part[(size_t)i*stride + c];
  sh[t] = s;
  __syncthreads();
  for (int o = 128; o; o >>= 1) {
    if (t < o) sh[t] += sh[t + o];
    __syncthreads();
  }
  if (t == 0) dsum[c] = sh[0];
}

// ---------------- bn1 affine from Gram (dsum[78]) ----------------
__global__ void k_bn1gram(const double* __restrict__ dsum,
                          const float* __restrict__ w_exp,
                          const float* __restrict__ g, const float* __restrict__ beta,
                          float* __restrict__ stats) {
  int c = threadIdx.x;
  if (c >= 36) return;
  float wv[12];
  float mean = 0.0f;
#pragma unroll
  for (int h = 0; h < 12; h++) { wv[h] = w_exp[c*12+h]; mean += wv[h]; }
  mean *= (1.0f/196.0f);
  double e2 = 0.0;
  int idx = 0;
#pragma unroll
  for (int h = 0; h < 12; h++)
#pragma unroll
    for (int h2 = h; h2 < 12; h2++, idx++) {
      double coef = (double)wv[h] * (double)wv[h2] * (h == h2 ? 1.0 : 2.0);
      e2 += coef * dsum[idx];
    }
  double var = e2 / (double)SAMP - (double)mean*mean;
  float a = g[c] * rsqrtf((float)var + 1e-5f);
  stats[c] = a;
  stats[36 + c] = beta[c] - mean * a;
}

// ---- pass A: expand (halo, 256 thr) + column-sweep dw, 2 groups of 18 ch
//      XCD-swizzled blocks; attn read as bf16
__global__ __launch_bounds__(256) void k_dlaA(const ushort* __restrict__ attn,
                                              const float* __restrict__ w_exp,
                                              const float* __restrict__ w_dw,
                                              const float* __restrict__ stats,
                                              ushort* __restrict__ rA,
                                              ushort* __restrict__ rB,
                                              ushort* __restrict__ rC,
                                              float* __restrict__ part) {
  __shared__ float  y_s[18*263];    // stride 263 (mod32=7)
  __shared__ ushort y2l[18*200];    // y2 fp16 transpose-staging
  __shared__ float  sbuf[2*252];    // per-(cl,col) s1/s2 partials
  const int t = threadIdx.x;
  const int bid = blockIdx.x;
  const int blk = (bid & 7)*784 + (bid >> 3);   // 6272 = 8*784, bijective XCD swizzle
  const int b = blk / 196, tile = blk - b*196;
  const int tyq = tile / 14;
  const int ty0 = tyq * 14, tx0 = (tile - tyq*14) * 14;
  const int hy = ty0 + (t >> 4) - 1, hx = tx0 + (t & 15) - 1;
  const bool inb = (hy >= 0) && (hy < 196) && (hx >= 0) && (hx < 196);
  float a[12];
#pragma unroll
  for (int ch = 0; ch < 12; ch++)
    a[ch] = inb ? b2f(attn[((size_t)(b*12+ch))*NN2 + (size_t)hy*196 + hx]) : 0.0f;

  const bool dwact = (t < 252);
  const int cl = t % 18, col = t / 18;      // dw role: channel-in-group, output column
  ushort* ydst = (blk < NCACHE) ? y2chunk_w(blk, rA, rB, rC) : nullptr;

  for (int g = 0; g < 2; g++) {
    __syncthreads();
#pragma unroll
    for (int c2 = 0; c2 < 18; c2++) {
      const int c = g*18 + c2;
      float y = 0.0f;
#pragma unroll
      for (int h = 0; h < 12; h++) y = fmaf(w_exp[c*12+h], a[h], y);
      y = y*stats[c] + stats[36+c];
      y = fminf(fmaxf(y, 0.0f), 6.0f);
      y_s[c2*263 + t] = inb ? y : 0.0f;
    }
    __syncthreads();
    if (dwact) {
      const int c = g*18 + cl;
      const float* ys = &y_s[cl*263 + col];
      const float* wd = &w_dw[c*9];
      float s1 = 0.0f, s2 = 0.0f;
      ushort y2h[14];
      float r0c0 = ys[0],  r0c1 = ys[1],  r0c2 = ys[2];
      float r1c0 = ys[16], r1c1 = ys[17], r1c2 = ys[18];
#pragma unroll
      for (int r = 0; r < 14; r++) {
        float r2c0 = ys[(r+2)*16], r2c1 = ys[(r+2)*16+1], r2c2 = ys[(r+2)*16+2];
        float y2 = wd[0]*r0c0;
        y2 = fmaf(wd[1], r0c1, y2); y2 = fmaf(wd[2], r0c2, y2);
        y2 = fmaf(wd[3], r1c0, y2); y2 = fmaf(wd[4], r1c1, y2);
        y2 = fmaf(wd[5], r1c2, y2); y2 = fmaf(wd[6], r2c0, y2);
        y2 = fmaf(wd[7], r2c1, y2); y2 = fmaf(wd[8], r2c2, y2);
        s1 += y2; s2 = fmaf(y2, y2, s2);
        y2h[r] = f2h_(y2);
        r0c0 = r1c0; r0c1 = r1c1; r0c2 = r1c2;
        r1c0 = r2c0; r1c1 = r2c1; r1c2 = r2c2;
      }
      sbuf[cl*14 + col] = s1;
      sbuf[252 + cl*14 + col] = s2;
#pragma unroll
      for (int r = 0; r < 14; r++) y2l[cl*200 + r*14 + col] = y2h[r];
    }
    __syncthreads();
    if (ydst) {
      // vectorized readout: 882 uint2 groups (4 ushorts each), 18 ch x 196 px
      for (int i = t; i < 882; i += 256) {
        int c2 = i / 49, q = i - c2*49;
        uint2 v = *(const uint2*)&y2l[c2*200 + q*4];
        *(uint2*)&ydst[g*3528 + c2*196 + q*4] = v;
      }
    }
    if (t < 36) {
      const int cc = t % 18, wh = t / 18;
      float s = 0.0f;
#pragma unroll
      for (int j = 0; j < 14; j++) s += sbuf[wh*252 + cc*14 + j];
      part[(size_t)blk*72 + wh*36 + g*18 + cc] = s;
    }
  }
}

// ---- pass B light: one pixel-pair per thread, 2 chunks per block (grid 3038) ----
__global__ __launch_bounds__(256) void k_dlaBlight(const ushort* __restrict__ rA,
                                                   const ushort* __restrict__ rB,
                                                   const ushort* __restrict__ rC,
                                                   const float* __restrict__ w_pro,
                                                   const float* __restrict__ stats,
                                                   float* __restrict__ zatt,
                                                   float* __restrict__ part) {
  __shared__ float red[4*24];
  const int t = threadIdx.x;
  const int blk = blockIdx.x;            // [0, NLB)
  const bool act = (t < 196);
  float s1[12] = {}, s2[12] = {};
  if (act) {
    const int chunk = blk*2 + (t / 98);  // [0, NCACHE)
    const int j = t % 98;                // pair index within chunk
    const int b = chunk / 196, tile = chunk - b*196;
    const int tyq = tile / 14;
    const int ty0 = tyq*14, tx0 = (tile - tyq*14)*14;
    const int p = 2*j;
    const int r = p / 14, cx = p - r*14; // 14 even -> pair stays in one row
    const ushort* src = y2chunk_r(chunk, rA, rB, rC) + p;
    float z0[12] = {}, z1[12] = {};
#pragma unroll
    for (int c = 0; c < 36; c++) {
      const unsigned u = *(const unsigned*)(src + c*196);
      float ya = h2f_((ushort)(u & 0xffffu));
      float yb = h2f_((ushort)(u >> 16));
      const float A2 = stats[72+c], B2 = stats[108+c];
      ya = fminf(fmaxf(fmaf(ya, A2, B2), 0.0f), 6.0f);
      yb = fminf(fmaxf(fmaf(yb, A2, B2), 0.0f), 6.0f);
#pragma unroll
      for (int cc = 0; cc < 12; cc++) {
        const float wp = w_pro[cc*36 + c];
        z0[cc] = fmaf(wp, ya, z0[cc]);
        z1[cc] = fmaf(wp, yb, z1[cc]);
      }
    }
    const int oy = ty0 + r, ox = tx0 + cx;
#pragma unroll
    for (int cc = 0; cc < 12; cc++) {
      *(float2*)&zatt[((size_t)(b*12+cc))*NN2 + (size_t)oy*196 + ox] =
          make_float2(z0[cc], z1[cc]);
      s1[cc] = z0[cc] + z1[cc];
      s2[cc] = z0[cc]*z0[cc] + z1[cc]*z1[cc];
    }
  }
#pragma unroll
  for (int cc = 0; cc < 12; cc++) {
#pragma unroll
    for (int off = 32; off; off >>= 1) {
      s1[cc] += __shfl_xor(s1[cc], off, 64);
      s2[cc] += __shfl_xor(s2[cc], off, 64);
    }
  }
  const int w = t >> 6;
  if ((t & 63) == 0) {
#pragma unroll
    for (int cc = 0; cc < 12; cc++) {
      red[w*24 + cc] = s1[cc];
      red[w*24 + 12 + cc] = s2[cc];
    }
  }
  __syncthreads();
  if (t < 24)
    part[(size_t)blk*24 + t] = red[t] + red[24+t] + red[48+t] + red[72+t];
}

// ---- pass B heavy: batch-31 full recompute (196 blocks); part rows NLB..; attn bf16 ----
__global__ __launch_bounds__(256) void k_dlaBheavy(const ushort* __restrict__ attn,
                                                   const float* __restrict__ w_exp,
                                                   const float* __restrict__ w_dw,
                                                   const float* __restrict__ w_pro,
                                                   const float* __restrict__ stats,
                                                   float* __restrict__ z31,
                                                   float* __restrict__ part) {
  __shared__ float y_s[12*256];
  __shared__ float z2[12*200];
  const int t = threadIdx.x;
  const int tile = blockIdx.x;
  const int b = 31;
  const int tyq = tile / 14;
  const int ty0 = tyq * 14, tx0 = (tile - tyq*14) * 14;
  const bool act = (t < 196);
  const int py = t / 14, px = t - py*14;
  const int oy = ty0 + py, ox = tx0 + px;
  float z[12] = {};
  const int hy = ty0 + (t >> 4) - 1, hx = tx0 + (t & 15) - 1;
  const bool inb = (hy >= 0) && (hy < 196) && (hx >= 0) && (hx < 196);
  float a[12];
#pragma unroll
  for (int ch = 0; ch < 12; ch++)
    a[ch] = inb ? b2f(attn[((size_t)(b*12+ch))*NN2 + (size_t)hy*196 + hx]) : 0.0f;
  const int base = (py+1)*16 + (px+1);
  for (int g = 0; g < 3; g++) {
    __syncthreads();
#pragma unroll
    for (int cl = 0; cl < 12; cl++) {
      const int c = g*12 + cl;
      float y = 0.0f;
#pragma unroll
      for (int h = 0; h < 12; h++) y = fmaf(w_exp[c*12+h], a[h], y);
      y = y*stats[c] + stats[36+c];
      y = fminf(fmaxf(y, 0.0f), 6.0f);
      y_s[cl*256 + t] = inb ? y : 0.0f;
    }
    __syncthreads();
    if (act) {
#pragma unroll
      for (int cl = 0; cl < 12; cl++) {
        const int c = g*12 + cl;
        const float* ys = &y_s[cl*256];
        float y2 = 0.0f;
#pragma unroll
        for (int di = 0; di < 3; di++)
#pragma unroll
          for (int dj = 0; dj < 3; dj++)
            y2 = fmaf(w_dw[c*9 + di*3 + dj], ys[base + (di-1)*16 + (dj-1)], y2);
        float y2c = y2*stats[72+c] + stats[108+c];
        y2c = fminf(fmaxf(y2c, 0.0f), 6.0f);
#pragma unroll
        for (int cc = 0; cc < 12; cc++) z[cc] = fmaf(w_pro[cc*36+c], y2c, z[cc]);
      }
    }
  }
  if (act) {
#pragma unroll
    for (int cc = 0; cc < 12; cc++)
      z31[(size_t)cc*NN2 + (size_t)oy*196 + ox] = z[cc];
  }
  // z stats
  __syncthreads();
  if (act) {
#pragma unroll
    for (int cc = 0; cc < 12; cc++) z2[cc*200 + t] = z[cc];
  }
  __syncthreads();
  const int rs = t >> 3, seg = t & 7;
  const int pix0 = seg*25;
  const int pcnt = (seg == 7) ? 21 : 25;
  if (rs < 24) {
    const int cl = rs % 12, wh = rs / 12;
    float s = 0.0f;
    for (int i = 0; i < pcnt; i++) {
      float v = z2[cl*200 + pix0 + i];
      s += wh ? v*v : v;
    }
    s += __shfl_xor(s, 1, 64);
    s += __shfl_xor(s, 2, 64);
    s += __shfl_xor(s, 4, 64);
    if (seg == 0)
      part[(size_t)(NLB + tile)*24 + wh*12 + cl] = s;
  }
}

// ---------------- dsum -> BN affine (36 ch, bn2) ----------------
__global__ void k_bnaffine36(const double* __restrict__ dsum,
                             const float* __restrict__ g, const float* __restrict__ beta,
                             float* __restrict__ stats, int off) {
  int c = threadIdx.x;
  if (c >= 36) return;
  double m = dsum[c] / (double)SAMP;
  double v = dsum[36 + c] / (double)SAMP - m*m;
  float a = g[c] * rsqrtf((float)v + 1e-5f);
  stats[off + c] = a;
  stats[off + 36 + c] = beta[c] - (float)m * a;
}

// ---------------- combined bn3 + adapt_bn affine (from dsum[24]) ----------------
__global__ void k_bnfinal(const double* __restrict__ dsum,
                          const float* __restrict__ g3, const float* __restrict__ b3,
                          const float* __restrict__ ag, const float* __restrict__ ab,
                          float* __restrict__ stats) {
  int c = threadIdx.x;
  if (c >= 12) return;
  (void)b3;
  double m = dsum[c] / (double)SAMP;
  double v = dsum[12 + c] / (double)SAMP - m*m;
  float r1 = rsqrtf((float)v + 1e-5f);
  float vt = g3[c]*g3[c]*(float)v*r1*r1;
  float r2 = rsqrtf(vt + 1e-5f);
  float A = g3[c]*ag[c]*r1*r2;
  stats[144 + c] = A;
  stats[156 + c] = ab[c] - (float)m*A;
}

// ---------------- V transpose: v16 [BH][196][64] -> vt [BH][64][224] bf16 (zero-pad) ----------------
__global__ __launch_bounds__(256) void k_vt(const ushort* __restrict__ v16,
                                            ushort* __restrict__ vt) {
  __shared__ ushort Vl[196*68];
  const int t = threadIdx.x, bh = blockIdx.x;
  const ushort* vp = v16 + (size_t)bh*Nn*Dd;
  for (int i = t; i < 1568; i += 256) {
    int row = i >> 3, ko = (i & 7)*8;
    *(uint4*)&Vl[row*68 + ko] = *(const uint4*)(vp + (size_t)row*64 + ko);
  }
  __syncthreads();
  ushort* dst = vt + (size_t)bh*64*224;
  for (int i = t; i < 64*28; i += 256) {
    int d = i / 28, q = i - d*28;
    ushort tmp[8];
#pragma unroll
    for (int j = 0; j < 8; j++) {
      int m = q*8 + j;
      tmp[j] = (m < 196) ? Vl[m*68 + d] : (ushort)0;
    }
    *(uint4*)&dst[d*224 + q*8] = *(const uint4*)tmp;
  }
}

// ---------------- MFMA PV: attn_r = z*Af+Bf (f32, in-place for b<31), O = P@Vt -> out_pre bf16 ----------------
__global__ __launch_bounds__(256) void k_pvm(const float* __restrict__ z31,
                                             const ushort* __restrict__ vt,
                                             const float* __restrict__ stats,
                                             float* __restrict__ attn_r,
                                             ushort* __restrict__ out_pre) {
  constexpr int STR = 232;
  __shared__ ushort U[32*STR];         // 14848 B: P tile only
  const int t = threadIdx.x;
  const int bh = blockIdx.x;
  const int r0 = blockIdx.y * 32;
  const int b = bh / 12, h = bh - b*12;
  const float Af = stats[144 + h], Bf = stats[156 + h];
  for (int i = t; i < 32*STR/8; i += 256)
    ((uint4*)U)[i] = make_uint4(0,0,0,0);
  __syncthreads();
  const int nvalid = (r0 + 32 <= 196) ? 32 : (196 - r0);
  float* arp = attn_r + (size_t)bh*NN2 + (size_t)r0*196;
  const float* zp = (b < 31) ? arp : (z31 + (size_t)h*NN2 + (size_t)r0*196);
  for (int idx = t; idx < nvalid*196; idx += 256) {
    int rr = idx / 196, m = idx - rr*196;
    float val = fmaf(zp[(size_t)rr*196 + m], Af, Bf);
    arp[(size_t)rr*196 + m] = val;
    U[rr*STR + m] = f2b(val);
  }
  __syncthreads();
  const int w = t >> 6, lane = t & 63;
  const int mt = w >> 1, ct = w & 1;
  const int lr = lane & 15, lk = lane >> 4;
  const ushort* vbase = vt + (size_t)bh*64*224;
#pragma unroll
  for (int cn = 0; cn < 2; cn++) {
    const int n0 = ct*32 + cn*16;
    f32x4 acc = {};
#pragma unroll
    for (int ks = 0; ks < 7; ks++) {
      bf16x8 af = *(const bf16x8*)&U[(mt*16 + lr)*STR + ks*32 + lk*8];
      bf16x8 bf = *(const bf16x8*)&vbase[(size_t)(n0 + lr)*224 + ks*32 + lk*8];
      acc = __builtin_amdgcn_mfma_f32_16x16x32_bf16(af, bf, acc, 0, 0, 0);
    }
#pragma unroll
    for (int r = 0; r < 4; r++) {
      int row = mt*16 + lk*4 + r;
      if (row < nvalid)
        out_pre[((size_t)(b*196 + r0 + row))*Cc + h*64 + n0 + lr] = f2b(acc[r]);
    }
  }
}

// ---------------- launch ----------------
extern "C" void kernel_launch(void* const* d_in, const int* in_sizes, int n_in,
                              void* d_out, int out_size, void* d_ws, size_t ws_size,
                              hipStream_t stream) {
  (void)in_sizes; (void)n_in; (void)out_size; (void)ws_size;
  const float* x      = (const float*)d_in[0];
  const float* w_qkv  = (const float*)d_in[1];
  const float* w_exp  = (const float*)d_in[2];
  const float* bn1_g  = (const float*)d_in[3];
  const float* bn1_b  = (const float*)d_in[4];
  const float* w_dw   = (const float*)d_in[5];
  const float* bn2_g  = (const float*)d_in[6];
  const float* bn2_b  = (const float*)d_in[7];
  const float* w_pro  = (const float*)d_in[8];
  const float* bn3_g  = (const float*)d_in[9];
  const float* bn3_b  = (const float*)d_in[10];
  const float* abn_g  = (const float*)d_in[11];
  const float* abn_b  = (const float*)d_in[12];
  const float* w_proj = (const float*)d_in[13];
  const float* b_proj = (const float*)d_in[14];

  float* out      = (float*)d_out;
  float* attn_out = out + (size_t)QSZ;      // d_out attn region: attn(bf16) -> z(b<31,f32) -> attn_r
  ushort* attnb   = (ushort*)attn_out;      // bf16 view of attention maps
  float* ws    = (float*)d_ws;
  ushort* vb16 = (ushort*)ws;               // [QSZ ushorts]
  ushort* opb  = (ushort*)ws + (size_t)QSZ; // [QSZ ushorts]: y2 cache rC -> out_pre
  float*  big  = ws + (size_t)QSZ;          // [ATT]: {q,k bf16} -> y2 cache rA
  ushort* qb16 = (ushort*)big;
  ushort* kb16 = qb16 + (size_t)QSZ;
  float* stats = ws + (size_t)QSZ + ATT;    // [256]
  float* part  = stats + 256;               // [6272*72]
  double* dsum = (double*)(part + (size_t)6272*72); // [96]
  float* z31   = (float*)(dsum + 96);       // [12*NN2] batch-31 z aux

  // staging in dead d_out region:
  ushort* xb   = (ushort*)out;              // x bf16
  ushort* wqb  = xb + (size_t)QSZ;          // w_qkv bf16
  ushort* rB   = (ushort*)out;              // y2 cache region B (after gemm<0> consumed xb/wqb)
  ushort* vtb  = (ushort*)out;              // V^T [384][64][224] (after rB consumed by dlaBlight)
  ushort* wpb  = (ushort*)part;             // w_proj bf16 (part dead after last reduce)

  k_cast <<<QSZ/2048, 256, 0, stream>>>(x, xb);
  k_cast <<<(2304*768)/2048, 256, 0, stream>>>(w_qkv, wqb);
  k_mfma_gemm<0><<<dim3(18, 49), 256, 0, stream>>>(xb, wqb, nullptr, qb16, kb16, vb16);
  k_qks      <<<1536, 256, 0, stream>>>(qb16, kb16, attnb);
  k_gram     <<<2048, 256, 0, stream>>>(attnb, part);
  k_reduce   <<<78, 256, 0, stream>>>(part, 2048, 78, dsum);
  k_bn1gram  <<<1, 64, 0, stream>>>(dsum, w_exp, bn1_g, bn1_b, stats);
  k_dlaA     <<<6272, 256, 0, stream>>>(attnb, w_exp, w_dw, stats,
                                        (ushort*)big, rB, opb, part);
  k_reduce   <<<72, 256, 0, stream>>>(part, 6272, 72, dsum);
  k_bnaffine36<<<1, 64, 0, stream>>>(dsum, bn2_g, bn2_b, stats, 72);
  k_dlaBheavy<<<196, 256, 0, stream>>>(attnb, w_exp, w_dw, w_pro, stats, z31, part);
  k_dlaBlight<<<NLB, 256, 0, stream>>>((const ushort*)big, rB, opb, w_pro, stats,
                                       attn_out, part);
  k_reduce   <<<24, 256, 0, stream>>>(part, NLB + 196, 24, dsum);
  k_bnfinal  <<<1, 64, 0, stream>>>(dsum, bn3_g, bn3_b, abn_g, abn_b, stats);
  k_vt       <<<384, 256, 0, stream>>>(vb16, vtb);                           // rB dead now
  k_cast     <<<(768*768)/2048, 256, 0, stream>>>(w_proj, wpb);
  k_pvm      <<<dim3(384, 7), 256, 0, stream>>>(z31, vtb, stats, attn_out, opb);
  k_mfma_gemm<1><<<dim3(6, 49), 256, 0, stream>>>(opb, wpb, b_proj, out, nullptr, nullptr);
}